// Round 1
// baseline (785.270 us; speedup 1.0000x reference)
//
#include <hip/hip_runtime.h>
#include <hip/hip_bf16.h>

// Problem constants (also derived defensively from in_sizes at launch)
#define NEG_SLOPE 0.2f

// ---------------------------------------------------------------------------
// CSR build: histogram of dst, exclusive scan (+1 self-loop per node), fill
// ---------------------------------------------------------------------------

__global__ void khist(const int* __restrict__ dst, int E, int* __restrict__ counts) {
    int i = blockIdx.x * blockDim.x + threadIdx.x;
    if (i < E) atomicAdd(&counts[dst[i]], 1);
}

// Single-block scan: row_ptr[i] = sum_{j<i} (counts[j]+1); row_ptr[n] = total.
__global__ __launch_bounds__(1024) void kscan(const int* __restrict__ counts,
                                              int* __restrict__ row_ptr,
                                              int* __restrict__ cursor, int n) {
    __shared__ int wsum[16];
    __shared__ int carry_s;
    int lane = threadIdx.x & 63;
    int wid  = threadIdx.x >> 6;
    if (threadIdx.x == 0) carry_s = 0;
    __syncthreads();
    int nchunk = (n + 1023) / 1024;
    for (int c = 0; c < nchunk; ++c) {
        int i = c * 1024 + (int)threadIdx.x;
        int v = (i < n) ? (counts[i] + 1) : 0;  // +1 = self loop
        // inclusive wave scan
        int x = v;
        #pragma unroll
        for (int off = 1; off < 64; off <<= 1) {
            int y = __shfl_up(x, off, 64);
            if (lane >= off) x += y;
        }
        if (lane == 63) wsum[wid] = x;
        __syncthreads();
        if (wid == 0) {
            int ws = (lane < 16) ? wsum[lane] : 0;
            #pragma unroll
            for (int off = 1; off < 16; off <<= 1) {
                int y = __shfl_up(ws, off, 64);
                if (lane >= off) ws += y;
            }
            if (lane < 16) wsum[lane] = ws;  // inclusive over waves
        }
        __syncthreads();
        int wave_excl = (wid == 0) ? 0 : wsum[wid - 1];
        int carry = carry_s;
        int excl = carry + wave_excl + (x - v);
        if (i < n) { row_ptr[i] = excl; cursor[i] = excl; }
        __syncthreads();  // all reads of carry_s / wsum done
        if (threadIdx.x == 0) carry_s = carry + wsum[15];
        __syncthreads();  // update visible before next chunk
    }
    if (threadIdx.x == 0) row_ptr[n] = carry_s;
}

__global__ void kfill(const int* __restrict__ src, const int* __restrict__ dst,
                      int E, int n, int* __restrict__ cursor, int* __restrict__ edge_src) {
    int i = blockIdx.x * blockDim.x + threadIdx.x;
    if (i < E) {
        int p = atomicAdd(&cursor[dst[i]], 1);
        edge_src[p] = src[i];
    } else if (i < E + n) {
        int v = i - E;  // self loop
        int p = atomicAdd(&cursor[v], 1);
        edge_src[p] = v;
    }
}

// ---------------------------------------------------------------------------
// fp32 tiled GEMM: C[M,Nn] = act(A[M,K] @ B[K,Nn] + bias). 64x64 tile, BK=16,
// 256 threads, 4x4 micro-tile per thread. K % 16 == 0, Nn % 64 == 0 assumed.
// ---------------------------------------------------------------------------
template <bool RELU>
__global__ __launch_bounds__(256) void kgemm(const float* __restrict__ A,
                                             const float* __restrict__ B,
                                             const float* __restrict__ bias,
                                             float* __restrict__ C,
                                             int M, int K, int Nn) {
    __shared__ float As[16][64];
    __shared__ float Bs[16][64];
    int t = threadIdx.x;
    int tx = t & 15, ty = t >> 4;
    int m0 = blockIdx.x * 64, n0 = blockIdx.y * 64;
    float acc[4][4] = {};
    for (int k0 = 0; k0 < K; k0 += 16) {
        {   // A tile: 64 rows x 16 cols
            int row = t >> 2;
            int col = (t & 3) * 4;
            int m = m0 + row;
            float4 v = make_float4(0.f, 0.f, 0.f, 0.f);
            if (m < M) v = *(const float4*)(A + (size_t)m * K + k0 + col);
            As[col + 0][row] = v.x; As[col + 1][row] = v.y;
            As[col + 2][row] = v.z; As[col + 3][row] = v.w;
        }
        {   // B tile: 16 rows x 64 cols
            int row = t >> 4;
            int col = (t & 15) * 4;
            float4 v = *(const float4*)(B + (size_t)(k0 + row) * Nn + n0 + col);
            *(float4*)&Bs[row][col] = v;
        }
        __syncthreads();
        #pragma unroll
        for (int k = 0; k < 16; ++k) {
            float a[4], b[4];
            *(float4*)a = *(const float4*)&As[k][ty * 4];
            *(float4*)b = *(const float4*)&Bs[k][tx * 4];
            #pragma unroll
            for (int i = 0; i < 4; ++i)
                #pragma unroll
                for (int j = 0; j < 4; ++j)
                    acc[i][j] += a[i] * b[j];
        }
        __syncthreads();
    }
    #pragma unroll
    for (int i = 0; i < 4; ++i) {
        int m = m0 + ty * 4 + i;
        if (m < M) {
            float4 o;
            float* op = (float*)&o;
            #pragma unroll
            for (int j = 0; j < 4; ++j) {
                float v = acc[i][j];
                if (bias) v += bias[n0 + tx * 4 + j];
                if (RELU) v = fmaxf(v, 0.f);
                op[j] = v;
            }
            *(float4*)(C + (size_t)m * Nn + n0 + tx * 4) = o;
        }
    }
}

// ---------------------------------------------------------------------------
// alpha1: as1[n][h] = sum_c h1[n,h,c]*a_src1[h,c]; ad1 likewise. Wave/node.
// ---------------------------------------------------------------------------
__global__ __launch_bounds__(256) void kalpha1(const float* __restrict__ h1,
                                               const float* __restrict__ a_src,
                                               const float* __restrict__ a_dst,
                                               float* __restrict__ as1,
                                               float* __restrict__ ad1, int n) {
    int wid = threadIdx.x >> 6, lane = threadIdx.x & 63;
    int node = blockIdx.x * 4 + wid;
    if (node >= n) return;
    float4 hv = ((const float4*)(h1 + (size_t)node * 256))[lane];
    float4 sv = ((const float4*)a_src)[lane];  // [2][128] flat
    float4 dv = ((const float4*)a_dst)[lane];
    float ps = hv.x * sv.x + hv.y * sv.y + hv.z * sv.z + hv.w * sv.w;
    float pd = hv.x * dv.x + hv.y * dv.y + hv.z * dv.z + hv.w * dv.w;
    #pragma unroll
    for (int off = 16; off >= 1; off >>= 1) {
        ps += __shfl_down(ps, off, 32);
        pd += __shfl_down(pd, off, 32);
    }
    if ((lane & 31) == 0) {
        int h = lane >> 5;
        as1[node * 2 + h] = ps;
        ad1[node * 2 + h] = pd;
    }
}

// ---------------------------------------------------------------------------
// Aggregation layer 1 (heads=2, C=128): block(256) per dst node.
// out1[n, t] = elu( (sum_e w_e * h1[src_e, t]) / (sum_e w_e) + b1[t] )
// w_e = exp(leaky_relu(as1[src,h] + ad1[n,h]))  (no max-subtraction; identical
// after normalization, exp args are O(10) -> safe in fp32)
// ---------------------------------------------------------------------------
__global__ __launch_bounds__(256) void kagg1(const float* __restrict__ h1,
                                             const float* __restrict__ as1,
                                             const float* __restrict__ ad1,
                                             const float* __restrict__ b1,
                                             const int* __restrict__ row_ptr,
                                             const int* __restrict__ edge_src,
                                             float* __restrict__ out1, int n) {
    __shared__ float w_lds[128];
    __shared__ int   s_lds[128];
    int node = blockIdx.x;
    int t = threadIdx.x;
    int beg = row_ptr[node], end = row_ptr[node + 1];
    int h_t = t >> 7;                       // head owned in phase B
    float adv = ad1[node * 2 + (t & 1)];    // head handled in phase A
    float acc = 0.f, ssum = 0.f;
    for (int base = beg; base < end; base += 128) {
        int cnt = min(128, end - base);
        int i = t >> 1, h = t & 1;
        if (i < cnt) {
            int s = edge_src[base + i];
            float e = as1[s * 2 + h] + adv;
            e = (e > 0.f) ? e : NEG_SLOPE * e;
            w_lds[i * 2 + h] = __expf(e);
            if (h == 0) s_lds[i] = s;
        }
        __syncthreads();
        for (int i2 = 0; i2 < cnt; ++i2) {
            float wv = w_lds[i2 * 2 + h_t];
            int s = s_lds[i2];
            acc += wv * h1[(size_t)s * 256 + t];
            ssum += wv;
        }
        __syncthreads();
    }
    float o = acc / (ssum + 1e-16f) + b1[t];
    out1[(size_t)node * 256 + t] = (o > 0.f) ? o : (__expf(o) - 1.f);
}

// ---------------------------------------------------------------------------
// Layer-2 linear (256 -> 4) + alpha2, wave per node.
// ---------------------------------------------------------------------------
__global__ __launch_bounds__(256) void kgemm2(const float* __restrict__ out1,
                                              const float* __restrict__ W2,
                                              const float* __restrict__ a_src2,
                                              const float* __restrict__ a_dst2,
                                              float* __restrict__ h2,
                                              float* __restrict__ as2,
                                              float* __restrict__ ad2, int n) {
    int wid = threadIdx.x >> 6, lane = threadIdx.x & 63;
    int node = blockIdx.x * 4 + wid;
    if (node >= n) return;
    float4 r = ((const float4*)(out1 + (size_t)node * 256))[lane];
    const float* w = W2 + lane * 16;  // rows 4l..4l+3 of [256,4]
    float4 w0 = *(const float4*)(w + 0);
    float4 w1 = *(const float4*)(w + 4);
    float4 w2v = *(const float4*)(w + 8);
    float4 w3 = *(const float4*)(w + 12);
    float a0 = r.x * w0.x + r.y * w1.x + r.z * w2v.x + r.w * w3.x;
    float a1 = r.x * w0.y + r.y * w1.y + r.z * w2v.y + r.w * w3.y;
    float a2 = r.x * w0.z + r.y * w1.z + r.z * w2v.z + r.w * w3.z;
    float a3 = r.x * w0.w + r.y * w1.w + r.z * w2v.w + r.w * w3.w;
    #pragma unroll
    for (int off = 32; off >= 1; off >>= 1) {
        a0 += __shfl_down(a0, off);
        a1 += __shfl_down(a1, off);
        a2 += __shfl_down(a2, off);
        a3 += __shfl_down(a3, off);
    }
    if (lane == 0) {
        h2[node * 4 + 0] = a0; h2[node * 4 + 1] = a1;
        h2[node * 4 + 2] = a2; h2[node * 4 + 3] = a3;
        as2[node] = a0 * a_src2[0] + a1 * a_src2[1] + a2 * a_src2[2] + a3 * a_src2[3];
        ad2[node] = a0 * a_dst2[0] + a1 * a_dst2[1] + a2 * a_dst2[2] + a3 * a_dst2[3];
    }
}

// ---------------------------------------------------------------------------
// Aggregation layer 2 (1 head, C=4): wave per node, 16 edges in flight.
// ---------------------------------------------------------------------------
__global__ __launch_bounds__(256) void kagg2(const float* __restrict__ h2,
                                             const float* __restrict__ as2,
                                             const float* __restrict__ ad2,
                                             const float* __restrict__ b2,
                                             const int* __restrict__ row_ptr,
                                             const int* __restrict__ edge_src,
                                             float* __restrict__ out, int n) {
    int wid = threadIdx.x >> 6, lane = threadIdx.x & 63;
    int node = blockIdx.x * 4 + wid;
    if (node >= n) return;
    int beg = row_ptr[node], end = row_ptr[node + 1];
    int j = lane & 3, ig = lane >> 2;
    float adv = ad2[node];
    float acc = 0.f, ssum = 0.f;
    for (int p = beg + ig; p < end; p += 16) {
        int s = edge_src[p];
        float e = as2[s] + adv;
        e = (e > 0.f) ? e : NEG_SLOPE * e;
        float wv = __expf(e);
        acc += wv * h2[s * 4 + j];
        ssum += wv;
    }
    #pragma unroll
    for (int off = 32; off >= 4; off >>= 1) {
        acc += __shfl_down(acc, off);
        ssum += __shfl_down(ssum, off);
    }
    if (lane < 4) out[node * 4 + j] = acc / (ssum + 1e-16f) + b2[j];
}

// ---------------------------------------------------------------------------
extern "C" void kernel_launch(void* const* d_in, const int* in_sizes, int n_in,
                              void* d_out, int out_size, void* d_ws, size_t ws_size,
                              hipStream_t stream) {
    const float* x      = (const float*)d_in[0];
    const int*   ei     = (const int*)d_in[1];
    const float* W_pre  = (const float*)d_in[2];
    const float* b_pre  = (const float*)d_in[3];
    const float* W1     = (const float*)d_in[4];
    const float* a_src1 = (const float*)d_in[5];
    const float* a_dst1 = (const float*)d_in[6];
    const float* b1     = (const float*)d_in[7];
    const float* W2     = (const float*)d_in[8];
    const float* a_src2 = (const float*)d_in[9];
    const float* a_dst2 = (const float*)d_in[10];
    const float* b2     = (const float*)d_in[11];
    float* out = (float*)d_out;

    const int DIN = 1024, HID = 128;
    const int E = in_sizes[1] / 2;
    const int N = in_sizes[0] / DIN;

    const int* esrc = ei;
    const int* edst = ei + E;

    // Workspace carve (bytes). Total ~103.4 MiB.
    char* ws = (char*)d_ws;
    size_t off = 0;
    float* h1 = (float*)(ws + off);   off += (size_t)N * 256 * 4;       // 51.2 MB
    float* h0 = (float*)(ws + off);                                     // 25.6 MB (dies after gemm1)
    float* out1 = h0;                 off += (size_t)N * 256 * 4;       // out1 overlays h0 region
    float* as1 = (float*)(ws + off);  off += (size_t)N * 2 * 4;
    float* ad1 = (float*)(ws + off);  off += (size_t)N * 2 * 4;
    float* h2  = (float*)(ws + off);  off += (size_t)N * 4 * 4;
    float* as2 = (float*)(ws + off);  off += (size_t)N * 4;
    float* ad2 = (float*)(ws + off);  off += (size_t)N * 4;
    int* row_ptr = (int*)(ws + off);  off += ((size_t)N + 16) * 4;
    int* cursor  = (int*)(ws + off);  off += (size_t)N * 4;
    int* counts  = (int*)(ws + off);  off += (size_t)N * 4;
    int* edge_src = (int*)(ws + off); off += (size_t)(E + N) * 4;

    // --- CSR build (same every launch; required since no state may persist) ---
    hipMemsetAsync(counts, 0, (size_t)N * 4, stream);
    khist<<<(E + 255) / 256, 256, 0, stream>>>(edst, E, counts);
    kscan<<<1, 1024, 0, stream>>>(counts, row_ptr, cursor, N);
    kfill<<<(E + N + 255) / 256, 256, 0, stream>>>(esrc, edst, E, N, cursor, edge_src);

    // --- h0 = relu(x @ W_pre + b_pre) : [N,1024]x[1024,128] ---
    {
        dim3 grid((N + 63) / 64, HID / 64);
        kgemm<true><<<grid, 256, 0, stream>>>(x, W_pre, b_pre, h0, N, DIN, HID);
    }
    // --- h1 = h0 @ W1 : [N,128]x[128,256] (bias deferred to aggregation) ---
    {
        dim3 grid((N + 63) / 64, 256 / 64);
        kgemm<false><<<grid, 256, 0, stream>>>(h0, W1, nullptr, h1, N, HID, 256);
    }
    // --- attention coefficients for layer 1 ---
    kalpha1<<<(N + 3) / 4, 256, 0, stream>>>(h1, a_src1, a_dst1, as1, ad1, N);
    // --- aggregate layer 1 + bias + elu -> out1 ---
    kagg1<<<N, 256, 0, stream>>>(h1, as1, ad1, b1, row_ptr, edge_src, out1, N);
    // --- layer-2 linear + alpha2 ---
    kgemm2<<<(N + 3) / 4, 256, 0, stream>>>(out1, W2, a_src2, a_dst2, h2, as2, ad2, N);
    // --- aggregate layer 2 + bias -> out ---
    kagg2<<<(N + 3) / 4, 256, 0, stream>>>(h2, as2, ad2, b2, row_ptr, edge_src, out, N);
}

// Round 2
// 673.061 us; speedup vs baseline: 1.1667x; 1.1667x over previous
//
#include <hip/hip_runtime.h>
#include <hip/hip_bf16.h>

#define NEG_SLOPE 0.2f

typedef __bf16 bf16x8 __attribute__((ext_vector_type(8)));
typedef unsigned short u16x8 __attribute__((ext_vector_type(8)));
typedef float f32x4 __attribute__((ext_vector_type(4)));
typedef unsigned short ushort_t;

// ---------------------------------------------------------------------------
// CSR build: histogram of dst, exclusive scan (+1 self-loop per node), fill
// ---------------------------------------------------------------------------

__global__ void khist(const int* __restrict__ dst, int E, int* __restrict__ counts) {
    int i = blockIdx.x * blockDim.x + threadIdx.x;
    if (i < E) atomicAdd(&counts[dst[i]], 1);
}

__global__ __launch_bounds__(1024) void kscan(const int* __restrict__ counts,
                                              int* __restrict__ row_ptr,
                                              int* __restrict__ cursor, int n) {
    __shared__ int wsum[16];
    __shared__ int carry_s;
    int lane = threadIdx.x & 63;
    int wid  = threadIdx.x >> 6;
    if (threadIdx.x == 0) carry_s = 0;
    __syncthreads();
    int nchunk = (n + 1023) / 1024;
    for (int c = 0; c < nchunk; ++c) {
        int i = c * 1024 + (int)threadIdx.x;
        int v = (i < n) ? (counts[i] + 1) : 0;  // +1 = self loop
        int x = v;
        #pragma unroll
        for (int off = 1; off < 64; off <<= 1) {
            int y = __shfl_up(x, off, 64);
            if (lane >= off) x += y;
        }
        if (lane == 63) wsum[wid] = x;
        __syncthreads();
        if (wid == 0) {
            int ws = (lane < 16) ? wsum[lane] : 0;
            #pragma unroll
            for (int off = 1; off < 16; off <<= 1) {
                int y = __shfl_up(ws, off, 64);
                if (lane >= off) ws += y;
            }
            if (lane < 16) wsum[lane] = ws;
        }
        __syncthreads();
        int wave_excl = (wid == 0) ? 0 : wsum[wid - 1];
        int carry = carry_s;
        int excl = carry + wave_excl + (x - v);
        if (i < n) { row_ptr[i] = excl; cursor[i] = excl; }
        __syncthreads();
        if (threadIdx.x == 0) carry_s = carry + wsum[15];
        __syncthreads();
    }
    if (threadIdx.x == 0) row_ptr[n] = carry_s;
}

__global__ void kfill(const int* __restrict__ src, const int* __restrict__ dst,
                      int E, int n, int* __restrict__ cursor, int* __restrict__ edge_src) {
    int i = blockIdx.x * blockDim.x + threadIdx.x;
    if (i < E) {
        int p = atomicAdd(&cursor[dst[i]], 1);
        edge_src[p] = src[i];
    } else if (i < E + n) {
        int v = i - E;
        int p = atomicAdd(&cursor[v], 1);
        edge_src[p] = v;
    }
}

// ---------------------------------------------------------------------------
// Weight prep: fp32 -> (hi, lo) bf16 split, swizzled to MFMA-B-frag order.
// Layout: dst elem ((k>>3)*Nn + n)*8 + (k&7)   (groups of 8 consecutive k)
// ---------------------------------------------------------------------------
__global__ void kprep(const float* __restrict__ Wpre, const float* __restrict__ W1,
                      ushort_t* __restrict__ PreH, ushort_t* __restrict__ PreL,
                      ushort_t* __restrict__ W1H, ushort_t* __restrict__ W1L) {
    int i = blockIdx.x * blockDim.x + threadIdx.x;
    if (i < 1024 * 128) {
        int k = i >> 7, n = i & 127;
        float f = Wpre[i];
        unsigned u = __float_as_uint(f);
        float lf = f - __uint_as_float(u & 0xffff0000u);
        int d = ((k >> 3) * 128 + n) * 8 + (k & 7);
        PreH[d] = (ushort_t)(u >> 16);
        PreL[d] = (ushort_t)(__float_as_uint(lf) >> 16);
    } else if (i < 1024 * 128 + 128 * 256) {
        int j2 = i - 1024 * 128;
        int k = j2 >> 8, n = j2 & 255;
        float f = W1[j2];
        unsigned u = __float_as_uint(f);
        float lf = f - __uint_as_float(u & 0xffff0000u);
        int d = ((k >> 3) * 256 + n) * 8 + (k & 7);
        W1H[d] = (ushort_t)(u >> 16);
        W1L[d] = (ushort_t)(__float_as_uint(lf) >> 16);
    }
}

// in-register fp32 -> hi/lo bf16 split of 8 values (truncation split; exact to
// ~2^-16 relative which is fp32-level after the 3-term MFMA product)
__device__ inline void split8(const float* v, bf16x8& hi, bf16x8& lo) {
    u16x8 h, l;
    #pragma unroll
    for (int i = 0; i < 8; ++i) {
        unsigned u = __float_as_uint(v[i]);
        h[i] = (ushort_t)(u >> 16);
        float lf = v[i] - __uint_as_float(u & 0xffff0000u);
        l[i] = (ushort_t)(__float_as_uint(lf) >> 16);
    }
    hi = __builtin_bit_cast(bf16x8, h);
    lo = __builtin_bit_cast(bf16x8, l);
}

// ---------------------------------------------------------------------------
// GEMM1: h0 = relu(x @ W_pre + b_pre).  M x 1024 x 128.
// Block = 64 rows x 128 cols, 4 waves; wave = 16 rows x 8 col-tiles (16x16).
// A: per-lane global loads + in-register split. B: LDS-staged from swizzled
// global hi/lo copies, one ds_read_b128 per fragment.
// 3 MFMAs per tile: Ahi*Bhi + Alo*Bhi + Ahi*Blo  (fp32-equivalent precision)
// ---------------------------------------------------------------------------
__global__ __launch_bounds__(256) void kgemm_mfma1(const float* __restrict__ A,
                                                   const ushort_t* __restrict__ Bhi,
                                                   const ushort_t* __restrict__ Blo,
                                                   const float* __restrict__ bias,
                                                   float* __restrict__ C, int M) {
    __shared__ ushort_t BsH[8192];  // [kc 8][n 128][j 8] bf16 = 16 KB
    __shared__ ushort_t BsL[8192];
    int t = threadIdx.x;
    int wid = t >> 6, lane = t & 63;
    int q = lane >> 4, l15 = lane & 15;
    int m0 = blockIdx.x * 64 + wid * 16;
    int m = m0 + l15;
    const float* arow = A + (size_t)(m < M ? m : 0) * 1024;

    f32x4 acc[8];
    #pragma unroll
    for (int c = 0; c < 8; ++c) acc[c] = (f32x4){0.f, 0.f, 0.f, 0.f};

    for (int kt = 0; kt < 16; ++kt) {
        __syncthreads();  // previous iteration's B reads complete
        {   // stage 16 KB hi + 16 KB lo (coalesced, conflict-free)
            const float4* sh = (const float4*)(Bhi + kt * 8192);
            const float4* sl = (const float4*)(Blo + kt * 8192);
            float4* dh = (float4*)BsH;
            float4* dl = (float4*)BsL;
            #pragma unroll
            for (int i = 0; i < 4; ++i) {
                dh[t + 256 * i] = sh[t + 256 * i];
                dl[t + 256 * i] = sl[t + 256 * i];
            }
        }
        __syncthreads();
        #pragma unroll
        for (int ks = 0; ks < 2; ++ks) {
            int k0 = kt * 64 + ks * 32;
            float av[8];
            *(float4*)&av[0] = *(const float4*)(arow + k0 + q * 8);
            *(float4*)&av[4] = *(const float4*)(arow + k0 + q * 8 + 4);
            bf16x8 ah, al;
            split8(av, ah, al);
            int kc = ks * 4 + q;
            #pragma unroll
            for (int c = 0; c < 8; ++c) {
                int off = (kc * 128 + c * 16 + l15) * 8;
                bf16x8 bh = *(const bf16x8*)(BsH + off);
                bf16x8 bl = *(const bf16x8*)(BsL + off);
                acc[c] = __builtin_amdgcn_mfma_f32_16x16x32_bf16(ah, bh, acc[c], 0, 0, 0);
                acc[c] = __builtin_amdgcn_mfma_f32_16x16x32_bf16(al, bh, acc[c], 0, 0, 0);
                acc[c] = __builtin_amdgcn_mfma_f32_16x16x32_bf16(ah, bl, acc[c], 0, 0, 0);
            }
        }
    }
    // D layout: row = q*4 + r, col = c*16 + l15  [m89-verified]
    #pragma unroll
    for (int c = 0; c < 8; ++c) {
        int n = c * 16 + l15;
        float bv = bias[n];
        #pragma unroll
        for (int r = 0; r < 4; ++r) {
            int mm = m0 + q * 4 + r;
            if (mm < M) C[(size_t)mm * 128 + n] = fmaxf(acc[c][r] + bv, 0.f);
        }
    }
}

// ---------------------------------------------------------------------------
// GEMM2: h1 = h0 @ W1.  M x 128 x 256.  Block = 64 rows x 128 cols (col group
// g = blockIdx.y); whole W1 half staged once in LDS (64 KB), K-loop unrolled.
// ---------------------------------------------------------------------------
__global__ __launch_bounds__(256) void kgemm_mfma2(const float* __restrict__ A,
                                                   const ushort_t* __restrict__ Bhi,
                                                   const ushort_t* __restrict__ Blo,
                                                   float* __restrict__ C, int M) {
    __shared__ ushort_t BsH[16384];  // [kc 16][n 128][j 8] = 32 KB
    __shared__ ushort_t BsL[16384];
    int t = threadIdx.x;
    int wid = t >> 6, lane = t & 63;
    int q = lane >> 4, l15 = lane & 15;
    int g = blockIdx.y;  // column half
    int m0 = blockIdx.x * 64 + wid * 16;
    int m = m0 + l15;
    const float* arow = A + (size_t)(m < M ? m : 0) * 128;

    {   // stage half of W1 (cols g*128..g*128+127): per kc, 2 KB contiguous
        const float4* sh = (const float4*)Bhi;
        const float4* sl = (const float4*)Blo;
        float4* dh = (float4*)BsH;
        float4* dl = (float4*)BsL;
        #pragma unroll
        for (int ii = 0; ii < 8; ++ii) {
            int i = t + ii * 256;           // 0..2047 float4s
            int kc = i >> 7, inner = i & 127;
            int s = kc * 256 + g * 128 + inner;
            dh[i] = sh[s];
            dl[i] = sl[s];
        }
    }
    // preload full A row slice (32 fp32 per lane)
    float av[32];
    #pragma unroll
    for (int ks = 0; ks < 4; ++ks) {
        *(float4*)&av[ks * 8 + 0] = *(const float4*)(arow + ks * 32 + q * 8);
        *(float4*)&av[ks * 8 + 4] = *(const float4*)(arow + ks * 32 + q * 8 + 4);
    }
    __syncthreads();

    f32x4 acc[8];
    #pragma unroll
    for (int c = 0; c < 8; ++c) acc[c] = (f32x4){0.f, 0.f, 0.f, 0.f};

    #pragma unroll
    for (int ks = 0; ks < 4; ++ks) {
        bf16x8 ah, al;
        split8(&av[ks * 8], ah, al);
        int kc = ks * 4 + q;
        #pragma unroll
        for (int c = 0; c < 8; ++c) {
            int off = (kc * 128 + c * 16 + l15) * 8;
            bf16x8 bh = *(const bf16x8*)(BsH + off);
            bf16x8 bl = *(const bf16x8*)(BsL + off);
            acc[c] = __builtin_amdgcn_mfma_f32_16x16x32_bf16(ah, bh, acc[c], 0, 0, 0);
            acc[c] = __builtin_amdgcn_mfma_f32_16x16x32_bf16(al, bh, acc[c], 0, 0, 0);
            acc[c] = __builtin_amdgcn_mfma_f32_16x16x32_bf16(ah, bl, acc[c], 0, 0, 0);
        }
    }
    #pragma unroll
    for (int c = 0; c < 8; ++c) {
        int n = g * 128 + c * 16 + l15;
        #pragma unroll
        for (int r = 0; r < 4; ++r) {
            int mm = m0 + q * 4 + r;
            if (mm < M) C[(size_t)mm * 256 + n] = acc[c][r];
        }
    }
}

// ---------------------------------------------------------------------------
// alpha1: as1[n][h] = sum_c h1[n,h,c]*a_src1[h,c]; ad1 likewise. Wave/node.
// ---------------------------------------------------------------------------
__global__ __launch_bounds__(256) void kalpha1(const float* __restrict__ h1,
                                               const float* __restrict__ a_src,
                                               const float* __restrict__ a_dst,
                                               float* __restrict__ as1,
                                               float* __restrict__ ad1, int n) {
    int wid = threadIdx.x >> 6, lane = threadIdx.x & 63;
    int node = blockIdx.x * 4 + wid;
    if (node >= n) return;
    float4 hv = ((const float4*)(h1 + (size_t)node * 256))[lane];
    float4 sv = ((const float4*)a_src)[lane];
    float4 dv = ((const float4*)a_dst)[lane];
    float ps = hv.x * sv.x + hv.y * sv.y + hv.z * sv.z + hv.w * sv.w;
    float pd = hv.x * dv.x + hv.y * dv.y + hv.z * dv.z + hv.w * dv.w;
    #pragma unroll
    for (int off = 16; off >= 1; off >>= 1) {
        ps += __shfl_down(ps, off, 32);
        pd += __shfl_down(pd, off, 32);
    }
    if ((lane & 31) == 0) {
        int h = lane >> 5;
        as1[node * 2 + h] = ps;
        ad1[node * 2 + h] = pd;
    }
}

// ---------------------------------------------------------------------------
// Aggregation layer 1 (heads=2, C=128): block(256) per dst node.
// ---------------------------------------------------------------------------
__global__ __launch_bounds__(256) void kagg1(const float* __restrict__ h1,
                                             const float* __restrict__ as1,
                                             const float* __restrict__ ad1,
                                             const float* __restrict__ b1,
                                             const int* __restrict__ row_ptr,
                                             const int* __restrict__ edge_src,
                                             float* __restrict__ out1, int n) {
    __shared__ float w_lds[128];
    __shared__ int   s_lds[128];
    int node = blockIdx.x;
    int t = threadIdx.x;
    int beg = row_ptr[node], end = row_ptr[node + 1];
    int h_t = t >> 7;
    float adv = ad1[node * 2 + (t & 1)];
    float acc = 0.f, ssum = 0.f;
    for (int base = beg; base < end; base += 128) {
        int cnt = min(128, end - base);
        int i = t >> 1, h = t & 1;
        if (i < cnt) {
            int s = edge_src[base + i];
            float e = as1[s * 2 + h] + adv;
            e = (e > 0.f) ? e : NEG_SLOPE * e;
            w_lds[i * 2 + h] = __expf(e);
            if (h == 0) s_lds[i] = s;
        }
        __syncthreads();
        for (int i2 = 0; i2 < cnt; ++i2) {
            float wv = w_lds[i2 * 2 + h_t];
            int s = s_lds[i2];
            acc += wv * h1[(size_t)s * 256 + t];
            ssum += wv;
        }
        __syncthreads();
    }
    float o = acc / (ssum + 1e-16f) + b1[t];
    out1[(size_t)node * 256 + t] = (o > 0.f) ? o : (__expf(o) - 1.f);
}

// ---------------------------------------------------------------------------
// Layer-2 linear (256 -> 4) + alpha2, wave per node.
// ---------------------------------------------------------------------------
__global__ __launch_bounds__(256) void klin2(const float* __restrict__ out1,
                                             const float* __restrict__ W2,
                                             const float* __restrict__ a_src2,
                                             const float* __restrict__ a_dst2,
                                             float* __restrict__ h2,
                                             float* __restrict__ as2,
                                             float* __restrict__ ad2, int n) {
    int wid = threadIdx.x >> 6, lane = threadIdx.x & 63;
    int node = blockIdx.x * 4 + wid;
    if (node >= n) return;
    float4 r = ((const float4*)(out1 + (size_t)node * 256))[lane];
    const float* w = W2 + lane * 16;
    float4 w0 = *(const float4*)(w + 0);
    float4 w1 = *(const float4*)(w + 4);
    float4 w2v = *(const float4*)(w + 8);
    float4 w3 = *(const float4*)(w + 12);
    float a0 = r.x * w0.x + r.y * w1.x + r.z * w2v.x + r.w * w3.x;
    float a1 = r.x * w0.y + r.y * w1.y + r.z * w2v.y + r.w * w3.y;
    float a2 = r.x * w0.z + r.y * w1.z + r.z * w2v.z + r.w * w3.z;
    float a3 = r.x * w0.w + r.y * w1.w + r.z * w2v.w + r.w * w3.w;
    #pragma unroll
    for (int off = 32; off >= 1; off >>= 1) {
        a0 += __shfl_down(a0, off);
        a1 += __shfl_down(a1, off);
        a2 += __shfl_down(a2, off);
        a3 += __shfl_down(a3, off);
    }
    if (lane == 0) {
        h2[node * 4 + 0] = a0; h2[node * 4 + 1] = a1;
        h2[node * 4 + 2] = a2; h2[node * 4 + 3] = a3;
        as2[node] = a0 * a_src2[0] + a1 * a_src2[1] + a2 * a_src2[2] + a3 * a_src2[3];
        ad2[node] = a0 * a_dst2[0] + a1 * a_dst2[1] + a2 * a_dst2[2] + a3 * a_dst2[3];
    }
}

// ---------------------------------------------------------------------------
// Aggregation layer 2 (1 head, C=4): wave per node, 16 edges in flight.
// ---------------------------------------------------------------------------
__global__ __launch_bounds__(256) void kagg2(const float* __restrict__ h2,
                                             const float* __restrict__ as2,
                                             const float* __restrict__ ad2,
                                             const float* __restrict__ b2,
                                             const int* __restrict__ row_ptr,
                                             const int* __restrict__ edge_src,
                                             float* __restrict__ out, int n) {
    int wid = threadIdx.x >> 6, lane = threadIdx.x & 63;
    int node = blockIdx.x * 4 + wid;
    if (node >= n) return;
    int beg = row_ptr[node], end = row_ptr[node + 1];
    int j = lane & 3, ig = lane >> 2;
    float adv = ad2[node];
    float acc = 0.f, ssum = 0.f;
    for (int p = beg + ig; p < end; p += 16) {
        int s = edge_src[p];
        float e = as2[s] + adv;
        e = (e > 0.f) ? e : NEG_SLOPE * e;
        float wv = __expf(e);
        acc += wv * h2[s * 4 + j];
        ssum += wv;
    }
    #pragma unroll
    for (int off = 32; off >= 4; off >>= 1) {
        acc += __shfl_down(acc, off);
        ssum += __shfl_down(ssum, off);
    }
    if (lane < 4) out[node * 4 + j] = acc / (ssum + 1e-16f) + b2[j];
}

// ---------------------------------------------------------------------------
extern "C" void kernel_launch(void* const* d_in, const int* in_sizes, int n_in,
                              void* d_out, int out_size, void* d_ws, size_t ws_size,
                              hipStream_t stream) {
    const float* x      = (const float*)d_in[0];
    const int*   ei     = (const int*)d_in[1];
    const float* W_pre  = (const float*)d_in[2];
    const float* b_pre  = (const float*)d_in[3];
    const float* W1     = (const float*)d_in[4];
    const float* a_src1 = (const float*)d_in[5];
    const float* a_dst1 = (const float*)d_in[6];
    const float* b1     = (const float*)d_in[7];
    const float* W2     = (const float*)d_in[8];
    const float* a_src2 = (const float*)d_in[9];
    const float* a_dst2 = (const float*)d_in[10];
    const float* b2     = (const float*)d_in[11];
    float* out = (float*)d_out;

    const int DIN = 1024;
    const int E = in_sizes[1] / 2;
    const int N = in_sizes[0] / DIN;

    const int* esrc = ei;
    const int* edst = ei + E;

    char* ws = (char*)d_ws;
    size_t off = 0;
    float* h1 = (float*)(ws + off);   off += (size_t)N * 256 * 4;
    float* h0 = (float*)(ws + off);                                 // dies after gemm2
    float* out1 = h0;                 off += (size_t)N * 256 * 4;   // overlays h0
    float* as1 = (float*)(ws + off);  off += (size_t)N * 2 * 4;
    float* ad1 = (float*)(ws + off);  off += (size_t)N * 2 * 4;
    float* h2  = (float*)(ws + off);  off += (size_t)N * 4 * 4;
    float* as2 = (float*)(ws + off);  off += (size_t)N * 4;
    float* ad2 = (float*)(ws + off);  off += (size_t)N * 4;
    int* row_ptr = (int*)(ws + off);  off += ((size_t)N + 16) * 4;
    int* cursor  = (int*)(ws + off);  off += (size_t)N * 4;
    int* counts  = (int*)(ws + off);  off += (size_t)N * 4;
    int* edge_src = (int*)(ws + off); off += (size_t)(E + N) * 4;
    ushort_t* PreH = (ushort_t*)(ws + off); off += 1024 * 128 * 2;
    ushort_t* PreL = (ushort_t*)(ws + off); off += 1024 * 128 * 2;
    ushort_t* W1H  = (ushort_t*)(ws + off); off += 128 * 256 * 2;
    ushort_t* W1L  = (ushort_t*)(ws + off); off += 128 * 256 * 2;

    // --- weight prep (tiny) + CSR build ---
    kprep<<<640, 256, 0, stream>>>(W_pre, W1, PreH, PreL, W1H, W1L);
    hipMemsetAsync(counts, 0, (size_t)N * 4, stream);
    khist<<<(E + 255) / 256, 256, 0, stream>>>(edst, E, counts);
    kscan<<<1, 1024, 0, stream>>>(counts, row_ptr, cursor, N);
    kfill<<<(E + N + 255) / 256, 256, 0, stream>>>(esrc, edst, E, N, cursor, edge_src);

    int Mb = (N + 63) / 64;
    // --- h0 = relu(x @ W_pre + b_pre) ---
    kgemm_mfma1<<<Mb, 256, 0, stream>>>(x, PreH, PreL, b_pre, h0, N);
    // --- h1 = h0 @ W1 ---
    {
        dim3 grid(Mb, 2);
        kgemm_mfma2<<<grid, 256, 0, stream>>>(h0, W1H, W1L, h1, N);
    }
    // --- attention coefficients for layer 1 ---
    kalpha1<<<(N + 3) / 4, 256, 0, stream>>>(h1, a_src1, a_dst1, as1, ad1, N);
    // --- aggregate layer 1 + bias + elu -> out1 ---
    kagg1<<<N, 256, 0, stream>>>(h1, as1, ad1, b1, row_ptr, edge_src, out1, N);
    // --- layer-2 linear + alpha2 ---
    klin2<<<(N + 3) / 4, 256, 0, stream>>>(out1, W2, a_src2, a_dst2, h2, as2, ad2, N);
    // --- aggregate layer 2 + bias -> out ---
    kagg2<<<(N + 3) / 4, 256, 0, stream>>>(h2, as2, ad2, b2, row_ptr, edge_src, out, N);
}

// Round 3
// 633.139 us; speedup vs baseline: 1.2403x; 1.0631x over previous
//
#include <hip/hip_runtime.h>
#include <hip/hip_bf16.h>

#define NEG_SLOPE 0.2f

typedef __bf16 bf16x8 __attribute__((ext_vector_type(8)));
typedef unsigned short u16x8 __attribute__((ext_vector_type(8)));
typedef float f32x4 __attribute__((ext_vector_type(4)));
typedef unsigned short ushort_t;

#define AS_GLOBAL(p) ((const __attribute__((address_space(1))) void*)(p))
#define AS_SHARED(p) ((__attribute__((address_space(3))) void*)(p))

// ---------------------------------------------------------------------------
// CSR build: histogram of dst, parallel exclusive scan (+1 self-loop), fill
// ---------------------------------------------------------------------------

__global__ void khist(const int* __restrict__ dst, int E, int* __restrict__ counts) {
    int i = blockIdx.x * blockDim.x + threadIdx.x;
    if (i < E) atomicAdd(&counts[dst[i]], 1);
}

// Per-block (1024 elems) exclusive scan of counts[i]+1; block totals to bsum.
__global__ __launch_bounds__(1024) void kscan_part(const int* __restrict__ counts,
                                                   int* __restrict__ row_ptr,
                                                   int* __restrict__ bsum, int n) {
    __shared__ int wsum[16];
    int t = threadIdx.x, lane = t & 63, wid = t >> 6;
    int i = blockIdx.x * 1024 + t;
    int v = (i < n) ? (counts[i] + 1) : 0;
    int x = v;
    #pragma unroll
    for (int off = 1; off < 64; off <<= 1) {
        int y = __shfl_up(x, off, 64);
        if (lane >= off) x += y;
    }
    if (lane == 63) wsum[wid] = x;
    __syncthreads();
    if (wid == 0) {
        int ws = (lane < 16) ? wsum[lane] : 0;
        #pragma unroll
        for (int off = 1; off < 16; off <<= 1) {
            int y = __shfl_up(ws, off, 64);
            if (lane >= off) ws += y;
        }
        if (lane < 16) wsum[lane] = ws;
    }
    __syncthreads();
    int wave_excl = (wid == 0) ? 0 : wsum[wid - 1];
    if (i < n) row_ptr[i] = wave_excl + (x - v);   // block-local exclusive
    if (t == 0) bsum[blockIdx.x] = wsum[15];       // block total
}

// Scan of block totals (G <= 64) + write row_ptr[n] = grand total.
__global__ void kscan_tops(const int* __restrict__ bsum, int* __restrict__ boff,
                           int* __restrict__ row_ptr, int G, int n) {
    int lane = threadIdx.x;
    int v = (lane < G) ? bsum[lane] : 0;
    int x = v;
    #pragma unroll
    for (int off = 1; off < 64; off <<= 1) {
        int y = __shfl_up(x, off, 64);
        if (lane >= off) x += y;
    }
    if (lane < G) boff[lane] = x - v;
    if (lane == 63) row_ptr[n] = x;
}

__global__ void kscan_add(int* __restrict__ row_ptr, const int* __restrict__ boff,
                          int* __restrict__ cursor, int n) {
    int i = blockIdx.x * blockDim.x + threadIdx.x;
    if (i < n) {
        int r = row_ptr[i] + boff[i >> 10];
        row_ptr[i] = r;
        cursor[i] = r;
    }
}

__global__ void kfill(const int* __restrict__ src, const int* __restrict__ dst,
                      int E, int n, int* __restrict__ cursor, int* __restrict__ edge_src) {
    int i = blockIdx.x * blockDim.x + threadIdx.x;
    if (i < E) {
        int p = atomicAdd(&cursor[dst[i]], 1);
        edge_src[p] = src[i];
    } else if (i < E + n) {
        int v = i - E;
        int p = atomicAdd(&cursor[v], 1);
        edge_src[p] = v;
    }
}

// ---------------------------------------------------------------------------
// Weight prep: fp32 -> (hi, lo) bf16 split, swizzled to MFMA-B-frag order.
// Layout: dst elem ((k>>3)*Nn + n)*8 + (k&7)
// ---------------------------------------------------------------------------
__global__ void kprep(const float* __restrict__ Wpre, const float* __restrict__ W1,
                      ushort_t* __restrict__ PreH, ushort_t* __restrict__ PreL,
                      ushort_t* __restrict__ W1H, ushort_t* __restrict__ W1L) {
    int i = blockIdx.x * blockDim.x + threadIdx.x;
    if (i < 1024 * 128) {
        int k = i >> 7, n = i & 127;
        float f = Wpre[i];
        unsigned u = __float_as_uint(f);
        float lf = f - __uint_as_float(u & 0xffff0000u);
        int d = ((k >> 3) * 128 + n) * 8 + (k & 7);
        PreH[d] = (ushort_t)(u >> 16);
        PreL[d] = (ushort_t)(__float_as_uint(lf) >> 16);
    } else if (i < 1024 * 128 + 128 * 256) {
        int j2 = i - 1024 * 128;
        int k = j2 >> 8, n = j2 & 255;
        float f = W1[j2];
        unsigned u = __float_as_uint(f);
        float lf = f - __uint_as_float(u & 0xffff0000u);
        int d = ((k >> 3) * 256 + n) * 8 + (k & 7);
        W1H[d] = (ushort_t)(u >> 16);
        W1L[d] = (ushort_t)(__float_as_uint(lf) >> 16);
    }
}

__device__ inline void split8(const float* v, bf16x8& hi, bf16x8& lo) {
    u16x8 h, l;
    #pragma unroll
    for (int i = 0; i < 8; ++i) {
        unsigned u = __float_as_uint(v[i]);
        h[i] = (ushort_t)(u >> 16);
        float lf = v[i] - __uint_as_float(u & 0xffff0000u);
        l[i] = (ushort_t)(__float_as_uint(lf) >> 16);
    }
    hi = __builtin_bit_cast(bf16x8, h);
    lo = __builtin_bit_cast(bf16x8, l);
}

// ---------------------------------------------------------------------------
// GEMM1: h0 = relu(x @ W_pre + b_pre).  M x 1024 x 128.
// m97-style 2-barrier K-loop: B staged via global_load_lds (16B, async, no
// VGPR roundtrip); A registers prefetched one K-tile ahead so their latency
// is hidden by a full tile of MFMA. Single 32 KB LDS buffer.
// ---------------------------------------------------------------------------
__global__ __launch_bounds__(256) void kgemm_mfma1(const float* __restrict__ A,
                                                   const ushort_t* __restrict__ Bhi,
                                                   const ushort_t* __restrict__ Blo,
                                                   const float* __restrict__ bias,
                                                   float* __restrict__ C, int M) {
    __shared__ __align__(16) ushort_t Bs[16384];  // hi [kc8][n128][j8] | lo at +8192
    int t = threadIdx.x;
    int wid = t >> 6, lane = t & 63;
    int q = lane >> 4, l15 = lane & 15;
    int m0 = blockIdx.x * 64 + wid * 16;
    int m = m0 + l15;
    const float* arow = A + (size_t)(m < M ? m : 0) * 1024;

    f32x4 acc[8];
    #pragma unroll
    for (int c = 0; c < 8; ++c) acc[c] = (f32x4){0.f, 0.f, 0.f, 0.f};

    float4 av[2][4];
    // prologue: A for kt=0 (drained at kt0's barrier2)
    #pragma unroll
    for (int ks = 0; ks < 2; ++ks) {
        av[0][ks * 2]     = *(const float4*)(arow + ks * 32 + q * 8);
        av[0][ks * 2 + 1] = *(const float4*)(arow + ks * 32 + q * 8 + 4);
    }

    #pragma unroll 2
    for (int kt = 0; kt < 16; ++kt) {
        int cur = kt & 1, nxt = cur ^ 1;
        __syncthreads();  // barrier1: Bs readers of kt-1 done
        {   // async-stage 32 KB of B (hi+lo) for this kt
            const ushort_t* sH = Bhi + kt * 8192;
            const ushort_t* sL = Blo + kt * 8192;
            #pragma unroll
            for (int i = 0; i < 4; ++i) {
                int ge = (i * 256 + t) * 8;
                int le = (i * 256 + (t & 0xC0)) * 8;  // wave-uniform LDS base
                __builtin_amdgcn_global_load_lds(AS_GLOBAL(sH + ge), AS_SHARED(Bs + le), 16, 0, 0);
                __builtin_amdgcn_global_load_lds(AS_GLOBAL(sL + ge), AS_SHARED(Bs + 8192 + le), 16, 0, 0);
            }
        }
        if (kt < 15) {  // prefetch A for kt+1 (in flight across this tile's MFMAs)
            const float* a2 = arow + (kt + 1) * 64;
            #pragma unroll
            for (int ks = 0; ks < 2; ++ks) {
                av[nxt][ks * 2]     = *(const float4*)(a2 + ks * 32 + q * 8);
                av[nxt][ks * 2 + 1] = *(const float4*)(a2 + ks * 32 + q * 8 + 4);
            }
        }
        __syncthreads();  // barrier2: vmcnt drain -> Bs staged, av[cur] ready
        #pragma unroll
        for (int ks = 0; ks < 2; ++ks) {
            bf16x8 ah, al;
            split8((const float*)&av[cur][ks * 2], ah, al);
            int kc = ks * 4 + q;
            #pragma unroll
            for (int c = 0; c < 8; ++c) {
                int off = (kc * 128 + c * 16 + l15) * 8;
                bf16x8 bh = *(const bf16x8*)(Bs + off);
                bf16x8 bl = *(const bf16x8*)(Bs + 8192 + off);
                acc[c] = __builtin_amdgcn_mfma_f32_16x16x32_bf16(ah, bh, acc[c], 0, 0, 0);
                acc[c] = __builtin_amdgcn_mfma_f32_16x16x32_bf16(al, bh, acc[c], 0, 0, 0);
                acc[c] = __builtin_amdgcn_mfma_f32_16x16x32_bf16(ah, bl, acc[c], 0, 0, 0);
            }
        }
    }
    // D layout: row = q*4 + r, col = c*16 + l15  [m89-verified]
    #pragma unroll
    for (int c = 0; c < 8; ++c) {
        int n = c * 16 + l15;
        float bv = bias[n];
        #pragma unroll
        for (int r = 0; r < 4; ++r) {
            int mm = m0 + q * 4 + r;
            if (mm < M) C[(size_t)mm * 128 + n] = fmaxf(acc[c][r] + bv, 0.f);
        }
    }
}

// ---------------------------------------------------------------------------
// GEMM2: h1 = h0 @ W1.  M x 128 x 256.  One-shot 64 KB B-stage via
// global_load_lds; A preloaded in the same window; single barrier; K unrolled.
// ---------------------------------------------------------------------------
__global__ __launch_bounds__(256) void kgemm_mfma2(const float* __restrict__ A,
                                                   const ushort_t* __restrict__ Bhi,
                                                   const ushort_t* __restrict__ Blo,
                                                   float* __restrict__ C, int M) {
    __shared__ __align__(16) ushort_t Bs[32768];  // hi [kc16][n128][j8] | lo at +16384
    int t = threadIdx.x;
    int wid = t >> 6, lane = t & 63;
    int q = lane >> 4, l15 = lane & 15;
    int g = blockIdx.y;
    int m0 = blockIdx.x * 64 + wid * 16;
    int m = m0 + l15;
    const float* arow = A + (size_t)(m < M ? m : 0) * 128;

    {   // stage half of W1 (cols g*128..+127): 32 wave-chunks of 1 KB each
        #pragma unroll
        for (int i = 0; i < 8; ++i) {
            int j = i * 4 + wid;                    // 0..31
            int kc = j >> 1, h1k = j & 1;
            int ge = ((kc * 256) + g * 128 + h1k * 64 + lane) * 8;
            int le = j * 512;                        // wave-uniform LDS base
            __builtin_amdgcn_global_load_lds(AS_GLOBAL(Bhi + ge), AS_SHARED(Bs + le), 16, 0, 0);
            __builtin_amdgcn_global_load_lds(AS_GLOBAL(Blo + ge), AS_SHARED(Bs + 16384 + le), 16, 0, 0);
        }
    }
    float av[32];
    #pragma unroll
    for (int ks = 0; ks < 4; ++ks) {
        *(float4*)&av[ks * 8 + 0] = *(const float4*)(arow + ks * 32 + q * 8);
        *(float4*)&av[ks * 8 + 4] = *(const float4*)(arow + ks * 32 + q * 8 + 4);
    }
    __syncthreads();  // drain: B staged + A regs ready

    f32x4 acc[8];
    #pragma unroll
    for (int c = 0; c < 8; ++c) acc[c] = (f32x4){0.f, 0.f, 0.f, 0.f};

    #pragma unroll
    for (int ks = 0; ks < 4; ++ks) {
        bf16x8 ah, al;
        split8(&av[ks * 8], ah, al);
        int kc = ks * 4 + q;
        #pragma unroll
        for (int c = 0; c < 8; ++c) {
            int off = (kc * 128 + c * 16 + l15) * 8;
            bf16x8 bh = *(const bf16x8*)(Bs + off);
            bf16x8 bl = *(const bf16x8*)(Bs + 16384 + off);
            acc[c] = __builtin_amdgcn_mfma_f32_16x16x32_bf16(ah, bh, acc[c], 0, 0, 0);
            acc[c] = __builtin_amdgcn_mfma_f32_16x16x32_bf16(al, bh, acc[c], 0, 0, 0);
            acc[c] = __builtin_amdgcn_mfma_f32_16x16x32_bf16(ah, bl, acc[c], 0, 0, 0);
        }
    }
    #pragma unroll
    for (int c = 0; c < 8; ++c) {
        int n = g * 128 + c * 16 + l15;
        #pragma unroll
        for (int r = 0; r < 4; ++r) {
            int mm = m0 + q * 4 + r;
            if (mm < M) C[(size_t)mm * 256 + n] = acc[c][r];
        }
    }
}

// ---------------------------------------------------------------------------
// alpha1: per-node attention dot products. Wave/node.
// ---------------------------------------------------------------------------
__global__ __launch_bounds__(256) void kalpha1(const float* __restrict__ h1,
                                               const float* __restrict__ a_src,
                                               const float* __restrict__ a_dst,
                                               float* __restrict__ as1,
                                               float* __restrict__ ad1, int n) {
    int wid = threadIdx.x >> 6, lane = threadIdx.x & 63;
    int node = blockIdx.x * 4 + wid;
    if (node >= n) return;
    float4 hv = ((const float4*)(h1 + (size_t)node * 256))[lane];
    float4 sv = ((const float4*)a_src)[lane];
    float4 dv = ((const float4*)a_dst)[lane];
    float ps = hv.x * sv.x + hv.y * sv.y + hv.z * sv.z + hv.w * sv.w;
    float pd = hv.x * dv.x + hv.y * dv.y + hv.z * dv.z + hv.w * dv.w;
    #pragma unroll
    for (int off = 16; off >= 1; off >>= 1) {
        ps += __shfl_down(ps, off, 32);
        pd += __shfl_down(pd, off, 32);
    }
    if ((lane & 31) == 0) {
        int h = lane >> 5;
        as1[node * 2 + h] = ps;
        ad1[node * 2 + h] = pd;
    }
}

// ---------------------------------------------------------------------------
// Aggregation layer 1 (heads=2, C=128): block(256) per dst node.
// ---------------------------------------------------------------------------
__global__ __launch_bounds__(256) void kagg1(const float* __restrict__ h1,
                                             const float* __restrict__ as1,
                                             const float* __restrict__ ad1,
                                             const float* __restrict__ b1,
                                             const int* __restrict__ row_ptr,
                                             const int* __restrict__ edge_src,
                                             float* __restrict__ out1, int n) {
    __shared__ float w_lds[128];
    __shared__ int   s_lds[128];
    int node = blockIdx.x;
    int t = threadIdx.x;
    int beg = row_ptr[node], end = row_ptr[node + 1];
    int h_t = t >> 7;
    float adv = ad1[node * 2 + (t & 1)];
    float acc = 0.f, ssum = 0.f;
    for (int base = beg; base < end; base += 128) {
        int cnt = min(128, end - base);
        int i = t >> 1, h = t & 1;
        if (i < cnt) {
            int s = edge_src[base + i];
            float e = as1[s * 2 + h] + adv;
            e = (e > 0.f) ? e : NEG_SLOPE * e;
            w_lds[i * 2 + h] = __expf(e);
            if (h == 0) s_lds[i] = s;
        }
        __syncthreads();
        #pragma unroll 4
        for (int i2 = 0; i2 < cnt; ++i2) {
            float wv = w_lds[i2 * 2 + h_t];
            int s = s_lds[i2];
            acc += wv * h1[(size_t)s * 256 + t];
            ssum += wv;
        }
        __syncthreads();
    }
    float o = acc / (ssum + 1e-16f) + b1[t];
    out1[(size_t)node * 256 + t] = (o > 0.f) ? o : (__expf(o) - 1.f);
}

// ---------------------------------------------------------------------------
// Layer-2 linear (256 -> 4) + alpha2, wave per node.
// ---------------------------------------------------------------------------
__global__ __launch_bounds__(256) void klin2(const float* __restrict__ out1,
                                             const float* __restrict__ W2,
                                             const float* __restrict__ a_src2,
                                             const float* __restrict__ a_dst2,
                                             float* __restrict__ h2,
                                             float* __restrict__ as2,
                                             float* __restrict__ ad2, int n) {
    int wid = threadIdx.x >> 6, lane = threadIdx.x & 63;
    int node = blockIdx.x * 4 + wid;
    if (node >= n) return;
    float4 r = ((const float4*)(out1 + (size_t)node * 256))[lane];
    const float* w = W2 + lane * 16;
    float4 w0 = *(const float4*)(w + 0);
    float4 w1 = *(const float4*)(w + 4);
    float4 w2v = *(const float4*)(w + 8);
    float4 w3 = *(const float4*)(w + 12);
    float a0 = r.x * w0.x + r.y * w1.x + r.z * w2v.x + r.w * w3.x;
    float a1 = r.x * w0.y + r.y * w1.y + r.z * w2v.y + r.w * w3.y;
    float a2 = r.x * w0.z + r.y * w1.z + r.z * w2v.z + r.w * w3.z;
    float a3 = r.x * w0.w + r.y * w1.w + r.z * w2v.w + r.w * w3.w;
    #pragma unroll
    for (int off = 32; off >= 1; off >>= 1) {
        a0 += __shfl_down(a0, off);
        a1 += __shfl_down(a1, off);
        a2 += __shfl_down(a2, off);
        a3 += __shfl_down(a3, off);
    }
    if (lane == 0) {
        h2[node * 4 + 0] = a0; h2[node * 4 + 1] = a1;
        h2[node * 4 + 2] = a2; h2[node * 4 + 3] = a3;
        as2[node] = a0 * a_src2[0] + a1 * a_src2[1] + a2 * a_src2[2] + a3 * a_src2[3];
        ad2[node] = a0 * a_dst2[0] + a1 * a_dst2[1] + a2 * a_dst2[2] + a3 * a_dst2[3];
    }
}

// ---------------------------------------------------------------------------
// Aggregation layer 2 (1 head, C=4): wave per node, 16 edges in flight.
// ---------------------------------------------------------------------------
__global__ __launch_bounds__(256) void kagg2(const float* __restrict__ h2,
                                             const float* __restrict__ as2,
                                             const float* __restrict__ ad2,
                                             const float* __restrict__ b2,
                                             const int* __restrict__ row_ptr,
                                             const int* __restrict__ edge_src,
                                             float* __restrict__ out, int n) {
    int wid = threadIdx.x >> 6, lane = threadIdx.x & 63;
    int node = blockIdx.x * 4 + wid;
    if (node >= n) return;
    int beg = row_ptr[node], end = row_ptr[node + 1];
    int j = lane & 3, ig = lane >> 2;
    float adv = ad2[node];
    float acc = 0.f, ssum = 0.f;
    for (int p = beg + ig; p < end; p += 16) {
        int s = edge_src[p];
        float e = as2[s] + adv;
        e = (e > 0.f) ? e : NEG_SLOPE * e;
        float wv = __expf(e);
        acc += wv * h2[s * 4 + j];
        ssum += wv;
    }
    #pragma unroll
    for (int off = 32; off >= 4; off >>= 1) {
        acc += __shfl_down(acc, off);
        ssum += __shfl_down(ssum, off);
    }
    if (lane < 4) out[node * 4 + j] = acc / (ssum + 1e-16f) + b2[j];
}

// ---------------------------------------------------------------------------
extern "C" void kernel_launch(void* const* d_in, const int* in_sizes, int n_in,
                              void* d_out, int out_size, void* d_ws, size_t ws_size,
                              hipStream_t stream) {
    const float* x      = (const float*)d_in[0];
    const int*   ei     = (const int*)d_in[1];
    const float* W_pre  = (const float*)d_in[2];
    const float* b_pre  = (const float*)d_in[3];
    const float* W1     = (const float*)d_in[4];
    const float* a_src1 = (const float*)d_in[5];
    const float* a_dst1 = (const float*)d_in[6];
    const float* b1     = (const float*)d_in[7];
    const float* W2     = (const float*)d_in[8];
    const float* a_src2 = (const float*)d_in[9];
    const float* a_dst2 = (const float*)d_in[10];
    const float* b2     = (const float*)d_in[11];
    float* out = (float*)d_out;

    const int DIN = 1024;
    const int E = in_sizes[1] / 2;
    const int N = in_sizes[0] / DIN;

    const int* esrc = ei;
    const int* edst = ei + E;

    char* ws = (char*)d_ws;
    size_t off = 0;
    float* h1 = (float*)(ws + off);   off += (size_t)N * 256 * 4;
    float* h0 = (float*)(ws + off);
    float* out1 = h0;                 off += (size_t)N * 256 * 4;
    float* as1 = (float*)(ws + off);  off += (size_t)N * 2 * 4;
    float* ad1 = (float*)(ws + off);  off += (size_t)N * 2 * 4;
    float* h2  = (float*)(ws + off);  off += (size_t)N * 4 * 4;
    float* as2 = (float*)(ws + off);  off += (size_t)N * 4;
    float* ad2 = (float*)(ws + off);  off += (size_t)N * 4;
    int* row_ptr = (int*)(ws + off);  off += ((size_t)N + 16) * 4;
    int* cursor  = (int*)(ws + off);  off += (size_t)N * 4;
    int* counts  = (int*)(ws + off);  off += (size_t)N * 4;
    int* bsum    = (int*)(ws + off);  off += 64 * 4;
    int* boff    = (int*)(ws + off);  off += 64 * 4;
    int* edge_src = (int*)(ws + off); off += (size_t)(E + N) * 4;
    ushort_t* PreH = (ushort_t*)(ws + off); off += 1024 * 128 * 2;
    ushort_t* PreL = (ushort_t*)(ws + off); off += 1024 * 128 * 2;
    ushort_t* W1H  = (ushort_t*)(ws + off); off += 128 * 256 * 2;
    ushort_t* W1L  = (ushort_t*)(ws + off); off += 128 * 256 * 2;

    int G = (N + 1023) / 1024;  // <= 64 for this problem

    // --- weight prep + CSR build ---
    kprep<<<640, 256, 0, stream>>>(W_pre, W1, PreH, PreL, W1H, W1L);
    hipMemsetAsync(counts, 0, (size_t)N * 4, stream);
    khist<<<(E + 255) / 256, 256, 0, stream>>>(edst, E, counts);
    kscan_part<<<G, 1024, 0, stream>>>(counts, row_ptr, bsum, N);
    kscan_tops<<<1, 64, 0, stream>>>(bsum, boff, row_ptr, G, N);
    kscan_add<<<(N + 255) / 256, 256, 0, stream>>>(row_ptr, boff, cursor, N);
    kfill<<<(E + N + 255) / 256, 256, 0, stream>>>(esrc, edst, E, N, cursor, edge_src);

    int Mb = (N + 63) / 64;
    // --- h0 = relu(x @ W_pre + b_pre) ---
    kgemm_mfma1<<<Mb, 256, 0, stream>>>(x, PreH, PreL, b_pre, h0, N);
    // --- h1 = h0 @ W1 ---
    {
        dim3 grid(Mb, 2);
        kgemm_mfma2<<<grid, 256, 0, stream>>>(h0, W1H, W1L, h1, N);
    }
    // --- attention coefficients for layer 1 ---
    kalpha1<<<(N + 3) / 4, 256, 0, stream>>>(h1, a_src1, a_dst1, as1, ad1, N);
    // --- aggregate layer 1 + bias + elu -> out1 ---
    kagg1<<<N, 256, 0, stream>>>(h1, as1, ad1, b1, row_ptr, edge_src, out1, N);
    // --- layer-2 linear + alpha2 ---
    klin2<<<(N + 3) / 4, 256, 0, stream>>>(out1, W2, a_src2, a_dst2, h2, as2, ad2, N);
    // --- aggregate layer 2 + bias -> out ---
    kagg2<<<(N + 3) / 4, 256, 0, stream>>>(h2, as2, ad2, b2, row_ptr, edge_src, out, N);
}

// Round 4
// 558.529 us; speedup vs baseline: 1.4060x; 1.1336x over previous
//
#include <hip/hip_runtime.h>
#include <hip/hip_bf16.h>

#define NEG_SLOPE 0.2f

typedef __bf16 bf16x8 __attribute__((ext_vector_type(8)));
typedef unsigned short u16x8 __attribute__((ext_vector_type(8)));
typedef float f32x4 __attribute__((ext_vector_type(4)));
typedef unsigned short ushort_t;

#define AS_GLOBAL(p) ((const __attribute__((address_space(1))) void*)(p))
#define AS_SHARED(p) ((__attribute__((address_space(3))) void*)(p))

// ---------------------------------------------------------------------------
// CSR build: histogram of dst, parallel exclusive scan (+1 self-loop), fill
// ---------------------------------------------------------------------------

__global__ void khist(const int* __restrict__ dst, int E, int* __restrict__ counts) {
    int i = blockIdx.x * blockDim.x + threadIdx.x;
    if (i < E) atomicAdd(&counts[dst[i]], 1);
}

__global__ __launch_bounds__(1024) void kscan_part(const int* __restrict__ counts,
                                                   int* __restrict__ row_ptr,
                                                   int* __restrict__ bsum, int n) {
    __shared__ int wsum[16];
    int t = threadIdx.x, lane = t & 63, wid = t >> 6;
    int i = blockIdx.x * 1024 + t;
    int v = (i < n) ? (counts[i] + 1) : 0;
    int x = v;
    #pragma unroll
    for (int off = 1; off < 64; off <<= 1) {
        int y = __shfl_up(x, off, 64);
        if (lane >= off) x += y;
    }
    if (lane == 63) wsum[wid] = x;
    __syncthreads();
    if (wid == 0) {
        int ws = (lane < 16) ? wsum[lane] : 0;
        #pragma unroll
        for (int off = 1; off < 16; off <<= 1) {
            int y = __shfl_up(ws, off, 64);
            if (lane >= off) ws += y;
        }
        if (lane < 16) wsum[lane] = ws;
    }
    __syncthreads();
    int wave_excl = (wid == 0) ? 0 : wsum[wid - 1];
    if (i < n) row_ptr[i] = wave_excl + (x - v);
    if (t == 0) bsum[blockIdx.x] = wsum[15];
}

__global__ void kscan_tops(const int* __restrict__ bsum, int* __restrict__ boff,
                           int* __restrict__ row_ptr, int G, int n) {
    int lane = threadIdx.x;
    int v = (lane < G) ? bsum[lane] : 0;
    int x = v;
    #pragma unroll
    for (int off = 1; off < 64; off <<= 1) {
        int y = __shfl_up(x, off, 64);
        if (lane >= off) x += y;
    }
    if (lane < G) boff[lane] = x - v;
    if (lane == 63) row_ptr[n] = x;
}

__global__ void kscan_add(int* __restrict__ row_ptr, const int* __restrict__ boff,
                          int* __restrict__ cursor, int n) {
    int i = blockIdx.x * blockDim.x + threadIdx.x;
    if (i < n) {
        int r = row_ptr[i] + boff[i >> 10];
        row_ptr[i] = r;
        cursor[i] = r;
    }
}

__global__ void kfill(const int* __restrict__ src, const int* __restrict__ dst,
                      int E, int n, int* __restrict__ cursor, int* __restrict__ edge_src) {
    int i = blockIdx.x * blockDim.x + threadIdx.x;
    if (i < E) {
        int p = atomicAdd(&cursor[dst[i]], 1);
        edge_src[p] = src[i];
    } else if (i < E + n) {
        int v = i - E;
        int p = atomicAdd(&cursor[v], 1);
        edge_src[p] = v;
    }
}

// ---------------------------------------------------------------------------
// Weight prep: fp32 -> (hi, lo) bf16 split, swizzled to MFMA-B-frag order.
// ---------------------------------------------------------------------------
__global__ void kprep(const float* __restrict__ Wpre, const float* __restrict__ W1,
                      ushort_t* __restrict__ PreH, ushort_t* __restrict__ PreL,
                      ushort_t* __restrict__ W1H, ushort_t* __restrict__ W1L) {
    int i = blockIdx.x * blockDim.x + threadIdx.x;
    if (i < 1024 * 128) {
        int k = i >> 7, n = i & 127;
        float f = Wpre[i];
        unsigned u = __float_as_uint(f);
        float lf = f - __uint_as_float(u & 0xffff0000u);
        int d = ((k >> 3) * 128 + n) * 8 + (k & 7);
        PreH[d] = (ushort_t)(u >> 16);
        PreL[d] = (ushort_t)(__float_as_uint(lf) >> 16);
    } else if (i < 1024 * 128 + 128 * 256) {
        int j2 = i - 1024 * 128;
        int k = j2 >> 8, n = j2 & 255;
        float f = W1[j2];
        unsigned u = __float_as_uint(f);
        float lf = f - __uint_as_float(u & 0xffff0000u);
        int d = ((k >> 3) * 256 + n) * 8 + (k & 7);
        W1H[d] = (ushort_t)(u >> 16);
        W1L[d] = (ushort_t)(__float_as_uint(lf) >> 16);
    }
}

__device__ inline void split8(const float* v, bf16x8& hi, bf16x8& lo) {
    u16x8 h, l;
    #pragma unroll
    for (int i = 0; i < 8; ++i) {
        unsigned u = __float_as_uint(v[i]);
        h[i] = (ushort_t)(u >> 16);
        float lf = v[i] - __uint_as_float(u & 0xffff0000u);
        l[i] = (ushort_t)(__float_as_uint(lf) >> 16);
    }
    hi = __builtin_bit_cast(bf16x8, h);
    lo = __builtin_bit_cast(bf16x8, l);
}

// ---------------------------------------------------------------------------
// GEMM1: h0 = relu(x @ W_pre + b_pre).  M x 1024 x 128.  m97-style 2-barrier
// K-loop, async B staging, A prefetched one K-tile ahead.
// ---------------------------------------------------------------------------
__global__ __launch_bounds__(256) void kgemm_mfma1(const float* __restrict__ A,
                                                   const ushort_t* __restrict__ Bhi,
                                                   const ushort_t* __restrict__ Blo,
                                                   const float* __restrict__ bias,
                                                   float* __restrict__ C, int M) {
    __shared__ __align__(16) ushort_t Bs[16384];
    int t = threadIdx.x;
    int wid = t >> 6, lane = t & 63;
    int q = lane >> 4, l15 = lane & 15;
    int m0 = blockIdx.x * 64 + wid * 16;
    int m = m0 + l15;
    const float* arow = A + (size_t)(m < M ? m : 0) * 1024;

    f32x4 acc[8];
    #pragma unroll
    for (int c = 0; c < 8; ++c) acc[c] = (f32x4){0.f, 0.f, 0.f, 0.f};

    float4 av[2][4];
    #pragma unroll
    for (int ks = 0; ks < 2; ++ks) {
        av[0][ks * 2]     = *(const float4*)(arow + ks * 32 + q * 8);
        av[0][ks * 2 + 1] = *(const float4*)(arow + ks * 32 + q * 8 + 4);
    }

    #pragma unroll 2
    for (int kt = 0; kt < 16; ++kt) {
        int cur = kt & 1, nxt = cur ^ 1;
        __syncthreads();
        {
            const ushort_t* sH = Bhi + kt * 8192;
            const ushort_t* sL = Blo + kt * 8192;
            #pragma unroll
            for (int i = 0; i < 4; ++i) {
                int ge = (i * 256 + t) * 8;
                int le = (i * 256 + (t & 0xC0)) * 8;
                __builtin_amdgcn_global_load_lds(AS_GLOBAL(sH + ge), AS_SHARED(Bs + le), 16, 0, 0);
                __builtin_amdgcn_global_load_lds(AS_GLOBAL(sL + ge), AS_SHARED(Bs + 8192 + le), 16, 0, 0);
            }
        }
        if (kt < 15) {
            const float* a2 = arow + (kt + 1) * 64;
            #pragma unroll
            for (int ks = 0; ks < 2; ++ks) {
                av[nxt][ks * 2]     = *(const float4*)(a2 + ks * 32 + q * 8);
                av[nxt][ks * 2 + 1] = *(const float4*)(a2 + ks * 32 + q * 8 + 4);
            }
        }
        __syncthreads();
        #pragma unroll
        for (int ks = 0; ks < 2; ++ks) {
            bf16x8 ah, al;
            split8((const float*)&av[cur][ks * 2], ah, al);
            int kc = ks * 4 + q;
            #pragma unroll
            for (int c = 0; c < 8; ++c) {
                int off = (kc * 128 + c * 16 + l15) * 8;
                bf16x8 bh = *(const bf16x8*)(Bs + off);
                bf16x8 bl = *(const bf16x8*)(Bs + 8192 + off);
                acc[c] = __builtin_amdgcn_mfma_f32_16x16x32_bf16(ah, bh, acc[c], 0, 0, 0);
                acc[c] = __builtin_amdgcn_mfma_f32_16x16x32_bf16(al, bh, acc[c], 0, 0, 0);
                acc[c] = __builtin_amdgcn_mfma_f32_16x16x32_bf16(ah, bl, acc[c], 0, 0, 0);
            }
        }
    }
    #pragma unroll
    for (int c = 0; c < 8; ++c) {
        int n = c * 16 + l15;
        float bv = bias[n];
        #pragma unroll
        for (int r = 0; r < 4; ++r) {
            int mm = m0 + q * 4 + r;
            if (mm < M) C[(size_t)mm * 128 + n] = fmaxf(acc[c][r] + bv, 0.f);
        }
    }
}

// ---------------------------------------------------------------------------
// GEMM2: h1 = h0 @ W1.  M x 128 x 256.  Output stored as bf16 (RNE) — h1 is
// only consumed by the attention gather, where bf16 halves the traffic.
// ---------------------------------------------------------------------------
__global__ __launch_bounds__(256) void kgemm_mfma2(const float* __restrict__ A,
                                                   const ushort_t* __restrict__ Bhi,
                                                   const ushort_t* __restrict__ Blo,
                                                   ushort_t* __restrict__ C, int M) {
    __shared__ __align__(16) ushort_t Bs[32768];
    int t = threadIdx.x;
    int wid = t >> 6, lane = t & 63;
    int q = lane >> 4, l15 = lane & 15;
    int g = blockIdx.y;
    int m0 = blockIdx.x * 64 + wid * 16;
    int m = m0 + l15;
    const float* arow = A + (size_t)(m < M ? m : 0) * 128;

    {
        #pragma unroll
        for (int i = 0; i < 8; ++i) {
            int j = i * 4 + wid;
            int kc = j >> 1, h1k = j & 1;
            int ge = ((kc * 256) + g * 128 + h1k * 64 + lane) * 8;
            int le = j * 512;
            __builtin_amdgcn_global_load_lds(AS_GLOBAL(Bhi + ge), AS_SHARED(Bs + le), 16, 0, 0);
            __builtin_amdgcn_global_load_lds(AS_GLOBAL(Blo + ge), AS_SHARED(Bs + 16384 + le), 16, 0, 0);
        }
    }
    float av[32];
    #pragma unroll
    for (int ks = 0; ks < 4; ++ks) {
        *(float4*)&av[ks * 8 + 0] = *(const float4*)(arow + ks * 32 + q * 8);
        *(float4*)&av[ks * 8 + 4] = *(const float4*)(arow + ks * 32 + q * 8 + 4);
    }
    __syncthreads();

    f32x4 acc[8];
    #pragma unroll
    for (int c = 0; c < 8; ++c) acc[c] = (f32x4){0.f, 0.f, 0.f, 0.f};

    #pragma unroll
    for (int ks = 0; ks < 4; ++ks) {
        bf16x8 ah, al;
        split8(&av[ks * 8], ah, al);
        int kc = ks * 4 + q;
        #pragma unroll
        for (int c = 0; c < 8; ++c) {
            int off = (kc * 128 + c * 16 + l15) * 8;
            bf16x8 bh = *(const bf16x8*)(Bs + off);
            bf16x8 bl = *(const bf16x8*)(Bs + 16384 + off);
            acc[c] = __builtin_amdgcn_mfma_f32_16x16x32_bf16(ah, bh, acc[c], 0, 0, 0);
            acc[c] = __builtin_amdgcn_mfma_f32_16x16x32_bf16(al, bh, acc[c], 0, 0, 0);
            acc[c] = __builtin_amdgcn_mfma_f32_16x16x32_bf16(ah, bl, acc[c], 0, 0, 0);
        }
    }
    #pragma unroll
    for (int c = 0; c < 8; ++c) {
        int n = g * 128 + c * 16 + l15;
        #pragma unroll
        for (int r = 0; r < 4; ++r) {
            int mm = m0 + q * 4 + r;
            if (mm < M) {
                unsigned u = __float_as_uint(acc[c][r]);
                unsigned b = (u + 0x7fffu + ((u >> 16) & 1u)) >> 16;  // RNE
                C[(size_t)mm * 256 + n] = (ushort_t)b;
            }
        }
    }
}

// ---------------------------------------------------------------------------
// alpha1 from bf16 h1: wave per node, lane l owns channels 4l..4l+3.
// ---------------------------------------------------------------------------
__global__ __launch_bounds__(256) void kalpha1(const ushort_t* __restrict__ h1b,
                                               const float* __restrict__ a_src,
                                               const float* __restrict__ a_dst,
                                               float* __restrict__ as1,
                                               float* __restrict__ ad1, int n) {
    int wid = threadIdx.x >> 6, lane = threadIdx.x & 63;
    int node = blockIdx.x * 4 + wid;
    if (node >= n) return;
    uint2 p = *(const uint2*)(h1b + (size_t)node * 256 + lane * 4);
    float h0 = __uint_as_float(p.x << 16);
    float h1v = __uint_as_float(p.x & 0xffff0000u);
    float h2v = __uint_as_float(p.y << 16);
    float h3 = __uint_as_float(p.y & 0xffff0000u);
    float4 sv = ((const float4*)a_src)[lane];
    float4 dv = ((const float4*)a_dst)[lane];
    float ps = h0 * sv.x + h1v * sv.y + h2v * sv.z + h3 * sv.w;
    float pd = h0 * dv.x + h1v * dv.y + h2v * dv.z + h3 * dv.w;
    #pragma unroll
    for (int off = 16; off >= 1; off >>= 1) {
        ps += __shfl_down(ps, off, 32);
        pd += __shfl_down(pd, off, 32);
    }
    if ((lane & 31) == 0) {
        int h = lane >> 5;
        as1[node * 2 + h] = ps;
        ad1[node * 2 + h] = pd;
    }
}

// ---------------------------------------------------------------------------
// Aggregation layer 1 (heads=2, C=256 total): 128-thread block per dst node.
// Thread t owns channels 2t, 2t+1 (head = t>>6); one uint load per edge gives
// both channels. Weights for a 64-edge chunk staged in LDS.
// ---------------------------------------------------------------------------
__global__ __launch_bounds__(128) void kagg1(const ushort_t* __restrict__ h1b,
                                             const float* __restrict__ as1,
                                             const float* __restrict__ ad1,
                                             const float* __restrict__ b1,
                                             const int* __restrict__ row_ptr,
                                             const int* __restrict__ edge_src,
                                             float* __restrict__ out1, int n) {
    __shared__ float w_lds[128];   // [edge 64][head 2]
    __shared__ int   s_lds[64];
    int node = blockIdx.x;
    int t = threadIdx.x;
    int beg = row_ptr[node], end = row_ptr[node + 1];
    int h_ch = t >> 6;                      // head of my channel pair
    float adv = ad1[node * 2 + (t & 1)];    // head used in phase A
    float acc0 = 0.f, acc1 = 0.f, ssum = 0.f;
    for (int base = beg; base < end; base += 64) {
        int cnt = min(64, end - base);
        int i = t >> 1, h = t & 1;
        if (i < cnt) {
            int s = edge_src[base + i];
            float e = as1[s * 2 + h] + adv;
            e = (e > 0.f) ? e : NEG_SLOPE * e;
            w_lds[i * 2 + h] = __expf(e);
            if (h == 0) s_lds[i] = s;
        }
        __syncthreads();
        #pragma unroll 4
        for (int i2 = 0; i2 < cnt; ++i2) {
            float wv = w_lds[i2 * 2 + h_ch];
            int s = s_lds[i2];
            unsigned p = *(const unsigned*)(h1b + (size_t)s * 256 + t * 2);
            acc0 += wv * __uint_as_float(p << 16);
            acc1 += wv * __uint_as_float(p & 0xffff0000u);
            ssum += wv;
        }
        __syncthreads();
    }
    float inv = 1.f / (ssum + 1e-16f);
    float o0 = acc0 * inv + b1[t * 2];
    float o1 = acc1 * inv + b1[t * 2 + 1];
    o0 = (o0 > 0.f) ? o0 : (__expf(o0) - 1.f);
    o1 = (o1 > 0.f) ? o1 : (__expf(o1) - 1.f);
    *(float2*)(out1 + (size_t)node * 256 + t * 2) = make_float2(o0, o1);
}

// ---------------------------------------------------------------------------
// Layer-2 linear (256 -> 4) + alpha2, wave per node.
// ---------------------------------------------------------------------------
__global__ __launch_bounds__(256) void klin2(const float* __restrict__ out1,
                                             const float* __restrict__ W2,
                                             const float* __restrict__ a_src2,
                                             const float* __restrict__ a_dst2,
                                             float* __restrict__ h2,
                                             float* __restrict__ as2,
                                             float* __restrict__ ad2, int n) {
    int wid = threadIdx.x >> 6, lane = threadIdx.x & 63;
    int node = blockIdx.x * 4 + wid;
    if (node >= n) return;
    float4 r = ((const float4*)(out1 + (size_t)node * 256))[lane];
    const float* w = W2 + lane * 16;
    float4 w0 = *(const float4*)(w + 0);
    float4 w1 = *(const float4*)(w + 4);
    float4 w2v = *(const float4*)(w + 8);
    float4 w3 = *(const float4*)(w + 12);
    float a0 = r.x * w0.x + r.y * w1.x + r.z * w2v.x + r.w * w3.x;
    float a1 = r.x * w0.y + r.y * w1.y + r.z * w2v.y + r.w * w3.y;
    float a2 = r.x * w0.z + r.y * w1.z + r.z * w2v.z + r.w * w3.z;
    float a3 = r.x * w0.w + r.y * w1.w + r.z * w2v.w + r.w * w3.w;
    #pragma unroll
    for (int off = 32; off >= 1; off >>= 1) {
        a0 += __shfl_down(a0, off);
        a1 += __shfl_down(a1, off);
        a2 += __shfl_down(a2, off);
        a3 += __shfl_down(a3, off);
    }
    if (lane == 0) {
        h2[node * 4 + 0] = a0; h2[node * 4 + 1] = a1;
        h2[node * 4 + 2] = a2; h2[node * 4 + 3] = a3;
        as2[node] = a0 * a_src2[0] + a1 * a_src2[1] + a2 * a_src2[2] + a3 * a_src2[3];
        ad2[node] = a0 * a_dst2[0] + a1 * a_dst2[1] + a2 * a_dst2[2] + a3 * a_dst2[3];
    }
}

// ---------------------------------------------------------------------------
// Aggregation layer 2 (1 head, C=4): wave per node, 16 edges in flight.
// ---------------------------------------------------------------------------
__global__ __launch_bounds__(256) void kagg2(const float* __restrict__ h2,
                                             const float* __restrict__ as2,
                                             const float* __restrict__ ad2,
                                             const float* __restrict__ b2,
                                             const int* __restrict__ row_ptr,
                                             const int* __restrict__ edge_src,
                                             float* __restrict__ out, int n) {
    int wid = threadIdx.x >> 6, lane = threadIdx.x & 63;
    int node = blockIdx.x * 4 + wid;
    if (node >= n) return;
    int beg = row_ptr[node], end = row_ptr[node + 1];
    int j = lane & 3, ig = lane >> 2;
    float adv = ad2[node];
    float acc = 0.f, ssum = 0.f;
    for (int p = beg + ig; p < end; p += 16) {
        int s = edge_src[p];
        float e = as2[s] + adv;
        e = (e > 0.f) ? e : NEG_SLOPE * e;
        float wv = __expf(e);
        acc += wv * h2[s * 4 + j];
        ssum += wv;
    }
    #pragma unroll
    for (int off = 32; off >= 4; off >>= 1) {
        acc += __shfl_down(acc, off);
        ssum += __shfl_down(ssum, off);
    }
    if (lane < 4) out[node * 4 + j] = acc / (ssum + 1e-16f) + b2[j];
}

// ---------------------------------------------------------------------------
extern "C" void kernel_launch(void* const* d_in, const int* in_sizes, int n_in,
                              void* d_out, int out_size, void* d_ws, size_t ws_size,
                              hipStream_t stream) {
    const float* x      = (const float*)d_in[0];
    const int*   ei     = (const int*)d_in[1];
    const float* W_pre  = (const float*)d_in[2];
    const float* b_pre  = (const float*)d_in[3];
    const float* W1     = (const float*)d_in[4];
    const float* a_src1 = (const float*)d_in[5];
    const float* a_dst1 = (const float*)d_in[6];
    const float* b1     = (const float*)d_in[7];
    const float* W2     = (const float*)d_in[8];
    const float* a_src2 = (const float*)d_in[9];
    const float* a_dst2 = (const float*)d_in[10];
    const float* b2     = (const float*)d_in[11];
    float* out = (float*)d_out;

    const int DIN = 1024;
    const int E = in_sizes[1] / 2;
    const int N = in_sizes[0] / DIN;

    const int* esrc = ei;
    const int* edst = ei + E;

    char* ws = (char*)d_ws;
    size_t off = 0;
    ushort_t* h1b = (ushort_t*)(ws + off); off += (size_t)N * 256 * 2;  // bf16 h1
    float* h0 = (float*)(ws + off);
    float* out1 = h0;                 off += (size_t)N * 256 * 4;       // overlays h0
    float* as1 = (float*)(ws + off);  off += (size_t)N * 2 * 4;
    float* ad1 = (float*)(ws + off);  off += (size_t)N * 2 * 4;
    float* h2  = (float*)(ws + off);  off += (size_t)N * 4 * 4;
    float* as2 = (float*)(ws + off);  off += (size_t)N * 4;
    float* ad2 = (float*)(ws + off);  off += (size_t)N * 4;
    int* row_ptr = (int*)(ws + off);  off += ((size_t)N + 16) * 4;
    int* cursor  = (int*)(ws + off);  off += (size_t)N * 4;
    int* counts  = (int*)(ws + off);  off += (size_t)N * 4;
    int* bsum    = (int*)(ws + off);  off += 64 * 4;
    int* boff    = (int*)(ws + off);  off += 64 * 4;
    int* edge_src = (int*)(ws + off); off += (size_t)(E + N) * 4;
    ushort_t* PreH = (ushort_t*)(ws + off); off += 1024 * 128 * 2;
    ushort_t* PreL = (ushort_t*)(ws + off); off += 1024 * 128 * 2;
    ushort_t* W1H  = (ushort_t*)(ws + off); off += 128 * 256 * 2;
    ushort_t* W1L  = (ushort_t*)(ws + off); off += 128 * 256 * 2;

    int G = (N + 1023) / 1024;

    // --- weight prep + CSR build ---
    kprep<<<640, 256, 0, stream>>>(W_pre, W1, PreH, PreL, W1H, W1L);
    hipMemsetAsync(counts, 0, (size_t)N * 4, stream);
    khist<<<(E + 255) / 256, 256, 0, stream>>>(edst, E, counts);
    kscan_part<<<G, 1024, 0, stream>>>(counts, row_ptr, bsum, N);
    kscan_tops<<<1, 64, 0, stream>>>(bsum, boff, row_ptr, G, N);
    kscan_add<<<(N + 255) / 256, 256, 0, stream>>>(row_ptr, boff, cursor, N);
    kfill<<<(E + N + 255) / 256, 256, 0, stream>>>(esrc, edst, E, N, cursor, edge_src);

    int Mb = (N + 63) / 64;
    // --- h0 = relu(x @ W_pre + b_pre) ---
    kgemm_mfma1<<<Mb, 256, 0, stream>>>(x, PreH, PreL, b_pre, h0, N);
    // --- h1 (bf16) = h0 @ W1 ---
    {
        dim3 grid(Mb, 2);
        kgemm_mfma2<<<grid, 256, 0, stream>>>(h0, W1H, W1L, h1b, N);
    }
    // --- attention coefficients for layer 1 ---
    kalpha1<<<(N + 3) / 4, 256, 0, stream>>>(h1b, a_src1, a_dst1, as1, ad1, N);
    // --- aggregate layer 1 + bias + elu -> out1 (fp32) ---
    kagg1<<<N, 128, 0, stream>>>(h1b, as1, ad1, b1, row_ptr, edge_src, out1, N);
    // --- layer-2 linear + alpha2 ---
    klin2<<<(N + 3) / 4, 256, 0, stream>>>(out1, W2, a_src2, a_dst2, h2, as2, ad2, N);
    // --- aggregate layer 2 + bias -> out ---
    kagg2<<<(N + 3) / 4, 256, 0, stream>>>(h2, as2, ad2, b2, row_ptr, edge_src, out, N);
}

// Round 5
// 532.295 us; speedup vs baseline: 1.4753x; 1.0493x over previous
//
#include <hip/hip_runtime.h>
#include <hip/hip_bf16.h>

#define NEG_SLOPE 0.2f

typedef __bf16 bf16x8 __attribute__((ext_vector_type(8)));
typedef unsigned short u16x8 __attribute__((ext_vector_type(8)));
typedef float f32x4 __attribute__((ext_vector_type(4)));
typedef unsigned short ushort_t;

#define AS_GLOBAL(p) ((const __attribute__((address_space(1))) void*)(p))
#define AS_SHARED(p) ((__attribute__((address_space(3))) void*)(p))

__device__ inline ushort_t rne_bf16(float f) {
    unsigned u = __float_as_uint(f);
    return (ushort_t)((u + 0x7fffu + ((u >> 16) & 1u)) >> 16);
}

// ---------------------------------------------------------------------------
// CSR build: histogram of dst, parallel exclusive scan (+1 self-loop), fill
// ---------------------------------------------------------------------------

__global__ void khist(const int* __restrict__ dst, int E, int* __restrict__ counts) {
    int i = blockIdx.x * blockDim.x + threadIdx.x;
    if (i < E) atomicAdd(&counts[dst[i]], 1);
}

__global__ __launch_bounds__(1024) void kscan_part(const int* __restrict__ counts,
                                                   int* __restrict__ row_ptr,
                                                   int* __restrict__ bsum, int n) {
    __shared__ int wsum[16];
    int t = threadIdx.x, lane = t & 63, wid = t >> 6;
    int i = blockIdx.x * 1024 + t;
    int v = (i < n) ? (counts[i] + 1) : 0;
    int x = v;
    #pragma unroll
    for (int off = 1; off < 64; off <<= 1) {
        int y = __shfl_up(x, off, 64);
        if (lane >= off) x += y;
    }
    if (lane == 63) wsum[wid] = x;
    __syncthreads();
    if (wid == 0) {
        int ws = (lane < 16) ? wsum[lane] : 0;
        #pragma unroll
        for (int off = 1; off < 16; off <<= 1) {
            int y = __shfl_up(ws, off, 64);
            if (lane >= off) ws += y;
        }
        if (lane < 16) wsum[lane] = ws;
    }
    __syncthreads();
    int wave_excl = (wid == 0) ? 0 : wsum[wid - 1];
    if (i < n) row_ptr[i] = wave_excl + (x - v);
    if (t == 0) bsum[blockIdx.x] = wsum[15];
}

__global__ void kscan_tops(const int* __restrict__ bsum, int* __restrict__ boff,
                           int* __restrict__ row_ptr, int G, int n) {
    int lane = threadIdx.x;
    int v = (lane < G) ? bsum[lane] : 0;
    int x = v;
    #pragma unroll
    for (int off = 1; off < 64; off <<= 1) {
        int y = __shfl_up(x, off, 64);
        if (lane >= off) x += y;
    }
    if (lane < G) boff[lane] = x - v;
    if (lane == 63) row_ptr[n] = x;
}

__global__ void kscan_add(int* __restrict__ row_ptr, const int* __restrict__ boff,
                          int* __restrict__ cursor, int n) {
    int i = blockIdx.x * blockDim.x + threadIdx.x;
    if (i < n) {
        int r = row_ptr[i] + boff[i >> 10];
        row_ptr[i] = r;
        cursor[i] = r;
    }
}

__global__ void kfill(const int* __restrict__ src, const int* __restrict__ dst,
                      int E, int n, int* __restrict__ cursor, int* __restrict__ edge_src) {
    int i = blockIdx.x * blockDim.x + threadIdx.x;
    if (i < E) {
        int p = atomicAdd(&cursor[dst[i]], 1);
        edge_src[p] = src[i];
    } else if (i < E + n) {
        int v = i - E;
        int p = atomicAdd(&cursor[v], 1);
        edge_src[p] = v;
    }
}

// ---------------------------------------------------------------------------
// Weight prep: W_pre -> hi/lo bf16 split (GEMM1 stays split-precision since x
// is fp32); W1 -> single bf16 (h0/h1 are bf16 anyway). Both swizzled to
// MFMA-B-frag order: elem (k,n) -> ((k>>3)*Nn + n)*8 + (k&7).
// ---------------------------------------------------------------------------
__global__ void kprep(const float* __restrict__ Wpre, const float* __restrict__ W1,
                      ushort_t* __restrict__ PreH, ushort_t* __restrict__ PreL,
                      ushort_t* __restrict__ W1b) {
    int i = blockIdx.x * blockDim.x + threadIdx.x;
    if (i < 1024 * 128) {
        int k = i >> 7, n = i & 127;
        float f = Wpre[i];
        unsigned u = __float_as_uint(f);
        float lf = f - __uint_as_float(u & 0xffff0000u);
        int d = ((k >> 3) * 128 + n) * 8 + (k & 7);
        PreH[d] = (ushort_t)(u >> 16);
        PreL[d] = (ushort_t)(__float_as_uint(lf) >> 16);
    } else if (i < 1024 * 128 + 128 * 256) {
        int j2 = i - 1024 * 128;
        int k = j2 >> 8, n = j2 & 255;
        int d = ((k >> 3) * 256 + n) * 8 + (k & 7);
        W1b[d] = rne_bf16(W1[j2]);
    }
}

__device__ inline void split8(const float* v, bf16x8& hi, bf16x8& lo) {
    u16x8 h, l;
    #pragma unroll
    for (int i = 0; i < 8; ++i) {
        unsigned u = __float_as_uint(v[i]);
        h[i] = (ushort_t)(u >> 16);
        float lf = v[i] - __uint_as_float(u & 0xffff0000u);
        l[i] = (ushort_t)(__float_as_uint(lf) >> 16);
    }
    hi = __builtin_bit_cast(bf16x8, h);
    lo = __builtin_bit_cast(bf16x8, l);
}

// ---------------------------------------------------------------------------
// GEMM1: h0b(bf16) = relu(x @ W_pre + b_pre).  M x 1024 x 128.
// m97-style 2-barrier K-loop, async B staging, A prefetched one tile ahead.
// ---------------------------------------------------------------------------
__global__ __launch_bounds__(256) void kgemm_mfma1(const float* __restrict__ A,
                                                   const ushort_t* __restrict__ Bhi,
                                                   const ushort_t* __restrict__ Blo,
                                                   const float* __restrict__ bias,
                                                   ushort_t* __restrict__ C, int M) {
    __shared__ __align__(16) ushort_t Bs[16384];
    int t = threadIdx.x;
    int wid = t >> 6, lane = t & 63;
    int q = lane >> 4, l15 = lane & 15;
    int m0 = blockIdx.x * 64 + wid * 16;
    int m = m0 + l15;
    const float* arow = A + (size_t)(m < M ? m : 0) * 1024;

    f32x4 acc[8];
    #pragma unroll
    for (int c = 0; c < 8; ++c) acc[c] = (f32x4){0.f, 0.f, 0.f, 0.f};

    float4 av[2][4];
    #pragma unroll
    for (int ks = 0; ks < 2; ++ks) {
        av[0][ks * 2]     = *(const float4*)(arow + ks * 32 + q * 8);
        av[0][ks * 2 + 1] = *(const float4*)(arow + ks * 32 + q * 8 + 4);
    }

    #pragma unroll 2
    for (int kt = 0; kt < 16; ++kt) {
        int cur = kt & 1, nxt = cur ^ 1;
        __syncthreads();
        {
            const ushort_t* sH = Bhi + kt * 8192;
            const ushort_t* sL = Blo + kt * 8192;
            #pragma unroll
            for (int i = 0; i < 4; ++i) {
                int ge = (i * 256 + t) * 8;
                int le = (i * 256 + (t & 0xC0)) * 8;
                __builtin_amdgcn_global_load_lds(AS_GLOBAL(sH + ge), AS_SHARED(Bs + le), 16, 0, 0);
                __builtin_amdgcn_global_load_lds(AS_GLOBAL(sL + ge), AS_SHARED(Bs + 8192 + le), 16, 0, 0);
            }
        }
        if (kt < 15) {
            const float* a2 = arow + (kt + 1) * 64;
            #pragma unroll
            for (int ks = 0; ks < 2; ++ks) {
                av[nxt][ks * 2]     = *(const float4*)(a2 + ks * 32 + q * 8);
                av[nxt][ks * 2 + 1] = *(const float4*)(a2 + ks * 32 + q * 8 + 4);
            }
        }
        __syncthreads();
        #pragma unroll
        for (int ks = 0; ks < 2; ++ks) {
            bf16x8 ah, al;
            split8((const float*)&av[cur][ks * 2], ah, al);
            int kc = ks * 4 + q;
            #pragma unroll
            for (int c = 0; c < 8; ++c) {
                int off = (kc * 128 + c * 16 + l15) * 8;
                bf16x8 bh = *(const bf16x8*)(Bs + off);
                bf16x8 bl = *(const bf16x8*)(Bs + 8192 + off);
                acc[c] = __builtin_amdgcn_mfma_f32_16x16x32_bf16(ah, bh, acc[c], 0, 0, 0);
                acc[c] = __builtin_amdgcn_mfma_f32_16x16x32_bf16(al, bh, acc[c], 0, 0, 0);
                acc[c] = __builtin_amdgcn_mfma_f32_16x16x32_bf16(ah, bl, acc[c], 0, 0, 0);
            }
        }
    }
    #pragma unroll
    for (int c = 0; c < 8; ++c) {
        int n = c * 16 + l15;
        float bv = bias[n];
        #pragma unroll
        for (int r = 0; r < 4; ++r) {
            int mm = m0 + q * 4 + r;
            if (mm < M) C[(size_t)mm * 128 + n] = rne_bf16(fmaxf(acc[c][r] + bv, 0.f));
        }
    }
}

// ---------------------------------------------------------------------------
// GEMM2 + fused alpha1: h1b(bf16) = h0b @ W1b, single-bf16 MFMA.
// Block = 64 rows x 128 cols; g = blockIdx.y = column half = head.
// Epilogue also computes as1/ad1 for head g via in-wave reduction over the
// 16 col-lanes (cols of head g are entirely within this block).
// ---------------------------------------------------------------------------
__global__ __launch_bounds__(256) void kgemm_mfma2(const ushort_t* __restrict__ Ab,
                                                   const ushort_t* __restrict__ W1b,
                                                   const float* __restrict__ a_src,
                                                   const float* __restrict__ a_dst,
                                                   ushort_t* __restrict__ C,
                                                   float* __restrict__ as1,
                                                   float* __restrict__ ad1, int M) {
    __shared__ __align__(16) ushort_t Bs[16384];  // [kc16][n128][j8] bf16 = 32 KB
    int t = threadIdx.x;
    int wid = t >> 6, lane = t & 63;
    int q = lane >> 4, l15 = lane & 15;
    int g = blockIdx.y;
    int m0 = blockIdx.x * 64 + wid * 16;
    int m = m0 + l15;
    const ushort_t* arow = Ab + (size_t)(m < M ? m : 0) * 128;

    {   // stage W1b half (cols g*128..+127): 32 wave-chunks of 1 KB
        #pragma unroll
        for (int i = 0; i < 8; ++i) {
            int j = i * 4 + wid;
            int kc = j >> 1, hk = j & 1;
            int ge = ((kc * 256) + g * 128 + hk * 64 + lane) * 8;
            int le = j * 512;
            __builtin_amdgcn_global_load_lds(AS_GLOBAL(W1b + ge), AS_SHARED(Bs + le), 16, 0, 0);
        }
    }
    bf16x8 af[4];
    #pragma unroll
    for (int ks = 0; ks < 4; ++ks)
        af[ks] = *(const bf16x8*)(arow + ks * 32 + q * 8);
    __syncthreads();

    f32x4 acc[8];
    #pragma unroll
    for (int c = 0; c < 8; ++c) acc[c] = (f32x4){0.f, 0.f, 0.f, 0.f};

    #pragma unroll
    for (int ks = 0; ks < 4; ++ks) {
        int kc = ks * 4 + q;
        #pragma unroll
        for (int c = 0; c < 8; ++c) {
            bf16x8 b = *(const bf16x8*)(Bs + (kc * 128 + c * 16 + l15) * 8);
            acc[c] = __builtin_amdgcn_mfma_f32_16x16x32_bf16(af[ks], b, acc[c], 0, 0, 0);
        }
    }
    // h1b store
    #pragma unroll
    for (int c = 0; c < 8; ++c) {
        int n = g * 128 + c * 16 + l15;
        #pragma unroll
        for (int r = 0; r < 4; ++r) {
            int mm = m0 + q * 4 + r;
            if (mm < M) C[(size_t)mm * 256 + n] = rne_bf16(acc[c][r]);
        }
    }
    // fused alpha: as1/ad1 for head g
    float asv[4] = {0.f, 0.f, 0.f, 0.f};
    float adv[4] = {0.f, 0.f, 0.f, 0.f};
    #pragma unroll
    for (int c = 0; c < 8; ++c) {
        float sa = a_src[g * 128 + c * 16 + l15];
        float da = a_dst[g * 128 + c * 16 + l15];
        #pragma unroll
        for (int r = 0; r < 4; ++r) {
            asv[r] += acc[c][r] * sa;
            adv[r] += acc[c][r] * da;
        }
    }
    #pragma unroll
    for (int off = 1; off <= 8; off <<= 1) {
        #pragma unroll
        for (int r = 0; r < 4; ++r) {
            asv[r] += __shfl_xor(asv[r], off, 64);
            adv[r] += __shfl_xor(adv[r], off, 64);
        }
    }
    if (l15 == 0) {
        #pragma unroll
        for (int r = 0; r < 4; ++r) {
            int node = m0 + q * 4 + r;
            if (node < M) {
                as1[node * 2 + g] = asv[r];
                ad1[node * 2 + g] = adv[r];
            }
        }
    }
}

// ---------------------------------------------------------------------------
// Aggregation layer 1 + fused layer-2 linear + alpha2.
// 128-thread block per dst node; thread t owns channels 2t,2t+1 (head t>>6).
// out1 (post-ELU) lives only in registers; block-reduces out1@W2 -> h2/as2/ad2.
// ---------------------------------------------------------------------------
__global__ __launch_bounds__(128) void kagg1(const ushort_t* __restrict__ h1b,
                                             const float* __restrict__ as1,
                                             const float* __restrict__ ad1,
                                             const float* __restrict__ b1,
                                             const float* __restrict__ W2,
                                             const float* __restrict__ a_src2,
                                             const float* __restrict__ a_dst2,
                                             const int* __restrict__ row_ptr,
                                             const int* __restrict__ edge_src,
                                             float* __restrict__ h2,
                                             float* __restrict__ as2,
                                             float* __restrict__ ad2, int n) {
    __shared__ float w_lds[128];   // [edge 64][head 2]
    __shared__ int   s_lds[64];
    __shared__ float red[2][4];
    int node = blockIdx.x;
    int t = threadIdx.x;
    int wid = t >> 6;
    int beg = row_ptr[node], end = row_ptr[node + 1];
    int h_ch = t >> 6;                      // head of my channel pair
    float advv = ad1[node * 2 + (t & 1)];   // head used in weight phase
    float acc0 = 0.f, acc1 = 0.f, ssum = 0.f;
    for (int base = beg; base < end; base += 64) {
        int cnt = min(64, end - base);
        int i = t >> 1, h = t & 1;
        if (i < cnt) {
            int s = edge_src[base + i];
            float e = as1[s * 2 + h] + advv;
            e = (e > 0.f) ? e : NEG_SLOPE * e;
            w_lds[i * 2 + h] = __expf(e);
            if (h == 0) s_lds[i] = s;
        }
        __syncthreads();
        #pragma unroll 4
        for (int i2 = 0; i2 < cnt; ++i2) {
            float wv = w_lds[i2 * 2 + h_ch];
            int s = s_lds[i2];
            unsigned p = *(const unsigned*)(h1b + (size_t)s * 256 + t * 2);
            acc0 += wv * __uint_as_float(p << 16);
            acc1 += wv * __uint_as_float(p & 0xffff0000u);
            ssum += wv;
        }
        __syncthreads();
    }
    float inv = 1.f / (ssum + 1e-16f);
    float o0 = acc0 * inv + b1[t * 2];
    float o1 = acc1 * inv + b1[t * 2 + 1];
    o0 = (o0 > 0.f) ? o0 : (__expf(o0) - 1.f);
    o1 = (o1 > 0.f) ? o1 : (__expf(o1) - 1.f);
    // fused linear: partial[j] = o0*W2[2t][j] + o1*W2[2t+1][j]
    float4 w0 = *(const float4*)(W2 + t * 8);
    float4 w1 = *(const float4*)(W2 + t * 8 + 4);
    float p0 = o0 * w0.x + o1 * w1.x;
    float p1 = o0 * w0.y + o1 * w1.y;
    float p2 = o0 * w0.z + o1 * w1.z;
    float p3 = o0 * w0.w + o1 * w1.w;
    #pragma unroll
    for (int off = 1; off < 64; off <<= 1) {
        p0 += __shfl_xor(p0, off, 64);
        p1 += __shfl_xor(p1, off, 64);
        p2 += __shfl_xor(p2, off, 64);
        p3 += __shfl_xor(p3, off, 64);
    }
    if ((t & 63) == 0) {
        red[wid][0] = p0; red[wid][1] = p1; red[wid][2] = p2; red[wid][3] = p3;
    }
    __syncthreads();
    if (t == 0) {
        float hv[4], s2 = 0.f, d2 = 0.f;
        #pragma unroll
        for (int j = 0; j < 4; ++j) {
            hv[j] = red[0][j] + red[1][j];
            h2[node * 4 + j] = hv[j];
            s2 += hv[j] * a_src2[j];
            d2 += hv[j] * a_dst2[j];
        }
        as2[node] = s2;
        ad2[node] = d2;
    }
}

// ---------------------------------------------------------------------------
// Aggregation layer 2 (1 head, C=4): wave per node, 16 edges in flight.
// ---------------------------------------------------------------------------
__global__ __launch_bounds__(256) void kagg2(const float* __restrict__ h2,
                                             const float* __restrict__ as2,
                                             const float* __restrict__ ad2,
                                             const float* __restrict__ b2,
                                             const int* __restrict__ row_ptr,
                                             const int* __restrict__ edge_src,
                                             float* __restrict__ out, int n) {
    int wid = threadIdx.x >> 6, lane = threadIdx.x & 63;
    int node = blockIdx.x * 4 + wid;
    if (node >= n) return;
    int beg = row_ptr[node], end = row_ptr[node + 1];
    int j = lane & 3, ig = lane >> 2;
    float adv = ad2[node];
    float acc = 0.f, ssum = 0.f;
    for (int p = beg + ig; p < end; p += 16) {
        int s = edge_src[p];
        float e = as2[s] + adv;
        e = (e > 0.f) ? e : NEG_SLOPE * e;
        float wv = __expf(e);
        acc += wv * h2[s * 4 + j];
        ssum += wv;
    }
    #pragma unroll
    for (int off = 32; off >= 4; off >>= 1) {
        acc += __shfl_down(acc, off);
        ssum += __shfl_down(ssum, off);
    }
    if (lane < 4) out[node * 4 + j] = acc / (ssum + 1e-16f) + b2[j];
}

// ---------------------------------------------------------------------------
extern "C" void kernel_launch(void* const* d_in, const int* in_sizes, int n_in,
                              void* d_out, int out_size, void* d_ws, size_t ws_size,
                              hipStream_t stream) {
    const float* x      = (const float*)d_in[0];
    const int*   ei     = (const int*)d_in[1];
    const float* W_pre  = (const float*)d_in[2];
    const float* b_pre  = (const float*)d_in[3];
    const float* W1     = (const float*)d_in[4];
    const float* a_src1 = (const float*)d_in[5];
    const float* a_dst1 = (const float*)d_in[6];
    const float* b1     = (const float*)d_in[7];
    const float* W2     = (const float*)d_in[8];
    const float* a_src2 = (const float*)d_in[9];
    const float* a_dst2 = (const float*)d_in[10];
    const float* b2     = (const float*)d_in[11];
    float* out = (float*)d_out;

    const int DIN = 1024;
    const int E = in_sizes[1] / 2;
    const int N = in_sizes[0] / DIN;

    const int* esrc = ei;
    const int* edst = ei + E;

    char* ws = (char*)d_ws;
    size_t off = 0;
    ushort_t* h1b = (ushort_t*)(ws + off); off += (size_t)N * 256 * 2;  // bf16 h1
    ushort_t* h0b = (ushort_t*)(ws + off); off += (size_t)N * 128 * 2;  // bf16 h0
    float* as1 = (float*)(ws + off);  off += (size_t)N * 2 * 4;
    float* ad1 = (float*)(ws + off);  off += (size_t)N * 2 * 4;
    float* h2  = (float*)(ws + off);  off += (size_t)N * 4 * 4;
    float* as2 = (float*)(ws + off);  off += (size_t)N * 4;
    float* ad2 = (float*)(ws + off);  off += (size_t)N * 4;
    int* row_ptr = (int*)(ws + off);  off += ((size_t)N + 16) * 4;
    int* cursor  = (int*)(ws + off);  off += (size_t)N * 4;
    int* counts  = (int*)(ws + off);  off += (size_t)N * 4;
    int* bsum    = (int*)(ws + off);  off += 64 * 4;
    int* boff    = (int*)(ws + off);  off += 64 * 4;
    int* edge_src = (int*)(ws + off); off += (size_t)(E + N) * 4;
    ushort_t* PreH = (ushort_t*)(ws + off); off += 1024 * 128 * 2;
    ushort_t* PreL = (ushort_t*)(ws + off); off += 1024 * 128 * 2;
    ushort_t* W1b  = (ushort_t*)(ws + off); off += 128 * 256 * 2;

    int G = (N + 1023) / 1024;

    // --- weight prep + CSR build ---
    kprep<<<640, 256, 0, stream>>>(W_pre, W1, PreH, PreL, W1b);
    hipMemsetAsync(counts, 0, (size_t)N * 4, stream);
    khist<<<(E + 255) / 256, 256, 0, stream>>>(edst, E, counts);
    kscan_part<<<G, 1024, 0, stream>>>(counts, row_ptr, bsum, N);
    kscan_tops<<<1, 64, 0, stream>>>(bsum, boff, row_ptr, G, N);
    kscan_add<<<(N + 255) / 256, 256, 0, stream>>>(row_ptr, boff, cursor, N);
    kfill<<<(E + N + 255) / 256, 256, 0, stream>>>(esrc, edst, E, N, cursor, edge_src);

    int Mb = (N + 63) / 64;
    // --- h0b = relu(x @ W_pre + b_pre) ---
    kgemm_mfma1<<<Mb, 256, 0, stream>>>(x, PreH, PreL, b_pre, h0b, N);
    // --- h1b = h0b @ W1b, + as1/ad1 fused ---
    {
        dim3 grid(Mb, 2);
        kgemm_mfma2<<<grid, 256, 0, stream>>>(h0b, W1b, a_src1, a_dst1, h1b, as1, ad1, N);
    }
    // --- aggregate layer 1 + bias + elu + layer-2 linear + alpha2 (fused) ---
    kagg1<<<N, 128, 0, stream>>>(h1b, as1, ad1, b1, W2, a_src2, a_dst2,
                                 row_ptr, edge_src, h2, as2, ad2, N);
    // --- aggregate layer 2 + bias -> out ---
    kagg2<<<(N + 3) / 4, 256, 0, stream>>>(h2, as2, ad2, b2, row_ptr, edge_src, out, N);
}